// Round 5
// baseline (57723.773 us; speedup 1.0000x reference)
//
#include <hip/hip_runtime.h>
#include <stdint.h>
#include <stddef.h>

#define B_  64
#define T_  2048
#define XD  256
#define H_  512
#define G4  2048          // 4*H
#define BT_ (B_*T_)       // 131072

typedef __attribute__((ext_vector_type(8))) _Float16 f16x8;
typedef __attribute__((ext_vector_type(4))) float f32x4;
typedef __attribute__((ext_vector_type(4))) unsigned int u32x4;
typedef __attribute__((ext_vector_type(4))) unsigned short us4;
typedef __attribute__((ext_vector_type(2))) _Float16 f16x2;

// ---------------- static device scratch (total ~1.42 GB, must stay < 2 GiB for PC32 reloc) ----
__device__ __attribute__((aligned(256))) unsigned short g_xh[(size_t)BT_*XD];         // 67 MB  x in fp16
__device__ __attribute__((aligned(256))) unsigned short g_w1h[(size_t)2*G4*XD];       // 2 MB   w_ih_l0 fp16
__device__ __attribute__((aligned(256))) unsigned short g_w2h[(size_t)2*G4*1024];     // 8 MB   w_ih_l1 fp16
__device__ __attribute__((aligned(256))) _Float16       g_xproj[(size_t)2*BT_*G4];    // 1.07 GB [dir][b][t][2048] fp16
__device__ __attribute__((aligned(256))) unsigned short g_out1[(size_t)BT_*1024];     // 268 MB [b][t][fwd512|bwd512] fp16
__device__ __attribute__((aligned(256))) unsigned short g_hbuf[2][2][2][B_*H_];       // [layer][dir][pingpong] fp16
__device__ __attribute__((aligned(256))) float          g_hlast[2][B_*H_];            // layer2 final h (fp32)
__device__ unsigned int g_cnt_sub[2][2][8][32];   // [layer][dir][subgroup][pad]
__device__ unsigned int g_cnt_root[2][2][32];     // [layer][dir][pad]

__device__ inline unsigned short f2h(float f) {
  _Float16 h = (_Float16)f;            // v_cvt_f16_f32, RNE
  return __builtin_bit_cast(unsigned short, h);
}
__device__ inline float sigf(float x)  { return 1.f/(1.f + __expf(-x)); }
__device__ inline float tanh_(float x) { return 1.f - 2.f/(__expf(2.f*x) + 1.f); }

// ---------------- init: zero h buffers + barrier counters (every call) ----------------
__global__ void k_init() {
  unsigned int i = blockIdx.x*256u + threadIdx.x;
  unsigned int stride = gridDim.x*256u;
  unsigned int* hb = (unsigned int*)&g_hbuf[0][0][0][0];
  for (unsigned int j = i; j < sizeof(g_hbuf)/4; j += stride) hb[j] = 0u;
  unsigned int* cs = (unsigned int*)&g_cnt_sub[0][0][0][0];
  for (unsigned int j = i; j < sizeof(g_cnt_sub)/4; j += stride) cs[j] = 0u;
  unsigned int* cr = (unsigned int*)&g_cnt_root[0][0][0];
  for (unsigned int j = i; j < sizeof(g_cnt_root)/4; j += stride) cr[j] = 0u;
}

// ---------------- fp32 -> fp16 converts ----------------
__global__ void k_cvt_x(const float* __restrict__ src) {
  const size_t n4 = (size_t)BT_*XD/4;
  for (size_t j = (size_t)blockIdx.x*blockDim.x + threadIdx.x; j < n4;
       j += (size_t)gridDim.x*blockDim.x) {
    float4 v = ((const float4*)src)[j];
    us4 o = { f2h(v.x), f2h(v.y), f2h(v.z), f2h(v.w) };
    ((us4*)g_xh)[j] = o;
  }
}
__global__ void k_cvt_w1(const float* __restrict__ src) {
  const size_t n4 = (size_t)2*G4*XD/4;
  for (size_t j = (size_t)blockIdx.x*blockDim.x + threadIdx.x; j < n4;
       j += (size_t)gridDim.x*blockDim.x) {
    float4 v = ((const float4*)src)[j];
    us4 o = { f2h(v.x), f2h(v.y), f2h(v.z), f2h(v.w) };
    ((us4*)g_w1h)[j] = o;
  }
}
__global__ void k_cvt_w2(const float* __restrict__ src) {
  const size_t n4 = (size_t)2*G4*1024/4;
  for (size_t j = (size_t)blockIdx.x*blockDim.x + threadIdx.x; j < n4;
       j += (size_t)gridDim.x*blockDim.x) {
    float4 v = ((const float4*)src)[j];
    us4 o = { f2h(v.x), f2h(v.y), f2h(v.z), f2h(v.w) };
    ((us4*)g_w2h)[j] = o;
  }
}

// ---------------- x_proj GEMM: out[d][m][n] = A[m]·W[d][n] + b_ih[n] + b_hh[n] -------
// 128x128 tile, BK=64, 4 waves (each 64x64), XOR-swizzled LDS, fp16 MFMA 16x16x32.
template<int LAYER>
__global__ __launch_bounds__(256) void k_xproj(const float* __restrict__ b_ih,
                                               const float* __restrict__ b_hh,
                                               const int* __restrict__ lens) {
  constexpr int K = (LAYER == 0) ? XD : 1024;
  const unsigned short* __restrict__ Abf = (LAYER == 0) ? g_xh : g_out1;
  const unsigned short* __restrict__ Wbf = (LAYER == 0) ? g_w1h : g_w2h;

  const int m0 = blockIdx.x*128;
  const int n0 = blockIdx.y*128;
  const int d  = blockIdx.z;
  const int bseq = m0 / T_;
  const int t0   = m0 % T_;
  if (t0 >= lens[bseq]) return;   // whole tile past this sequence's length

  __shared__ unsigned short As[128*64];
  __shared__ unsigned short Bs[128*64];

  const int tid  = threadIdx.x;
  const int lane = tid & 63;
  const int wv   = tid >> 6;
  const int moff = (wv >> 1)*64;
  const int noff = (wv & 1)*64;

  f32x4 acc[4][4] = {};

  const unsigned short* Ag = Abf + (size_t)m0*K;
  const unsigned short* Wg = Wbf + ((size_t)d*G4 + n0)*K;

  for (int k0 = 0; k0 < K; k0 += 64) {
    __syncthreads();
    #pragma unroll
    for (int p = 0; p < 4; ++p) {
      int sidx = p*256 + tid;
      int row = sidx >> 3;
      int ch  = sidx & 7;
      u32x4 va = *(const u32x4*)(Ag + (size_t)row*K + k0 + ch*8);
      u32x4 vb = *(const u32x4*)(Wg + (size_t)row*K + k0 + ch*8);
      int wb = row*128 + ((ch ^ (row & 7)) << 4);
      *(u32x4*)((char*)As + wb) = va;
      *(u32x4*)((char*)Bs + wb) = vb;
    }
    __syncthreads();
    #pragma unroll
    for (int kt = 0; kt < 2; ++kt) {
      int slot = kt*4 + (lane >> 4);
      f16x8 af[4], bfv[4];
      #pragma unroll
      for (int mt = 0; mt < 4; ++mt) {
        int r = moff + mt*16 + (lane & 15);
        af[mt] = *(const f16x8*)((const char*)As + r*128 + ((slot ^ (r & 7)) << 4));
      }
      #pragma unroll
      for (int nt = 0; nt < 4; ++nt) {
        int r = noff + nt*16 + (lane & 15);
        bfv[nt] = *(const f16x8*)((const char*)Bs + r*128 + ((slot ^ (r & 7)) << 4));
      }
      #pragma unroll
      for (int mt = 0; mt < 4; ++mt)
        #pragma unroll
        for (int nt = 0; nt < 4; ++nt)
          acc[mt][nt] = __builtin_amdgcn_mfma_f32_16x16x32_f16(af[mt], bfv[nt], acc[mt][nt], 0, 0, 0);
    }
  }

  #pragma unroll
  for (int nt = 0; nt < 4; ++nt) {
    const int col = n0 + noff + nt*16 + (lane & 15);
    const float bias = b_ih[d*G4 + col] + b_hh[d*G4 + col];
    #pragma unroll
    for (int mt = 0; mt < 4; ++mt) {
      const int row = m0 + moff + mt*16 + (lane >> 4)*4;
      _Float16* op = g_xproj + ((size_t)d*BT_ + row)*G4 + col;
      #pragma unroll
      for (int j = 0; j < 4; ++j)
        op[(size_t)j*G4] = (_Float16)(acc[mt][nt][j] + bias);
    }
  }
}

// ---------------- recurrent scan ----------------
// grid = 128 blocks: dir = bid&1, wg = bid>>1 (64 WGs per direction).
// WG wg owns h-columns [wg*8, wg*8+8) i.e. gate columns {g*512 + wg*8 + j}.
// Per step: g = h(64x512,fp16) @ Whh_sliceT (MFMA) + xproj; gates -> h,c; h -> global dbuf.
// Cross-WG barrier: 2-level device-scope atomic counters + agent fences (cross-XCD safe).
template<int LAYER>
__global__ __launch_bounds__(256) void k_scan(const float* __restrict__ w_hh,
                                              const int* __restrict__ lens) {
  const int dir  = blockIdx.x & 1;
  const int wg   = blockIdx.x >> 1;
  const int tid  = threadIdx.x;
  const int lane = tid & 63;
  const int wv   = tid >> 6;

  __shared__ unsigned short Wl[32*512];   // 32 KB, XOR-swizzled, rows = 32 gate cols (fp16)
  __shared__ float gs[64*33];             // gate scratch, padded stride 33

  // load + convert this WG's W_hh slice (rows: gate*512 + wg*8 + hc)
  for (int i = tid; i < 32*256; i += 256) {
    int e = i*2;
    int row = e >> 9;
    int k   = e & 511;
    int gate = row >> 3, hc = row & 7;
    int grow = gate*H_ + wg*8 + hc;
    const float* wsrc = w_hh + ((size_t)dir*G4 + grow)*H_ + k;
    unsigned int pk = (unsigned int)f2h(wsrc[0]) | ((unsigned int)f2h(wsrc[1]) << 16);
    int byte = row*1024 + ((((k*2) >> 4) ^ (row & 7)) << 4) + ((k*2) & 15);
    *(unsigned int*)((char*)Wl + byte) = pk;
  }

  const int myseq = tid >> 2;            // thread owns (myseq, hcA) and (myseq, hcA+1)
  const int hcA   = (tid & 3)*2;
  const int mylen = lens[myseq];         // int32 input!
  const int maxlen = lens[0];            // sorted descending
  const int col0  = wg*8;
  const int arow  = wv*16 + (lane & 15);
  const int koff  = (lane >> 4)*8;
  float c0 = 0.f, c1 = 0.f;
  unsigned int hold = 0u;                // packed fp16 pair, current h for my items

  unsigned short* hbuf0 = &g_hbuf[LAYER][dir][0][0];
  unsigned short* hbuf1 = &g_hbuf[LAYER][dir][1][0];
  unsigned int* cnt_sub  = &g_cnt_sub[LAYER][dir][wg >> 3][0];
  unsigned int* cnt_root = &g_cnt_root[LAYER][dir][0];

  __syncthreads();

  for (int s = 0; s < maxlen; ++s) {
    const unsigned short* hread = (s & 1) ? hbuf1 : hbuf0;
    unsigned short* hwrite      = (s & 1) ? hbuf0 : hbuf1;
    const bool act = s < mylen;
    const int pos  = dir ? (mylen - 1 - s) : s;

    float xg[8];
    if (act) {
      const unsigned int* xp32 = (const unsigned int*)
          (g_xproj + (((size_t)dir*B_ + myseq)*T_ + pos)*G4 + col0);
      #pragma unroll
      for (int g = 0; g < 4; ++g) {
        unsigned int pk = xp32[g*(H_/2) + (hcA >> 1)];
        f16x2 p = __builtin_bit_cast(f16x2, pk);
        xg[2*g]   = (float)p[0];
        xg[2*g+1] = (float)p[1];
      }
    }

    // recurrent GEMM: wave wv computes seqs [16wv,16wv+16) x 32 gate cols
    f32x4 acc0 = {0.f,0.f,0.f,0.f};
    f32x4 acc1 = {0.f,0.f,0.f,0.f};
    #pragma unroll
    for (int kt = 0; kt < 16; ++kt) {
      f16x8 a = *(const f16x8*)(hread + (size_t)arow*H_ + kt*32 + koff);
      int slot = kt*4 + (lane >> 4);
      int r0 = lane & 15;
      int r1 = 16 + r0;
      f16x8 b0 = *(const f16x8*)((const char*)Wl + r0*1024 + ((slot ^ (r0 & 7)) << 4));
      f16x8 b1 = *(const f16x8*)((const char*)Wl + r1*1024 + ((slot ^ (r1 & 7)) << 4));
      acc0 = __builtin_amdgcn_mfma_f32_16x16x32_f16(a, b0, acc0, 0, 0, 0);
      acc1 = __builtin_amdgcn_mfma_f32_16x16x32_f16(a, b1, acc1, 0, 0, 0);
    }
    #pragma unroll
    for (int j = 0; j < 4; ++j) {
      int srow = wv*16 + (lane >> 4)*4 + j;
      gs[srow*33 + (lane & 15)]      = acc0[j];
      gs[srow*33 + 16 + (lane & 15)] = acc1[j];
    }
    // gs producer lanes and consumer lanes are in the SAME wave -> in-order DS ops.
    if (act) {
      const int q = myseq*33;
      float vi0 = gs[q + hcA]        + xg[0];
      float vi1 = gs[q + hcA + 1]    + xg[1];
      float vf0 = gs[q + 8 + hcA]    + xg[2];
      float vf1 = gs[q + 8 + hcA + 1]+ xg[3];
      float vg0 = gs[q + 16 + hcA]   + xg[4];
      float vg1 = gs[q + 16 + hcA+1] + xg[5];
      float vo0 = gs[q + 24 + hcA]   + xg[6];
      float vo1 = gs[q + 24 + hcA+1] + xg[7];
      float i0 = sigf(vi0), f0 = sigf(vf0), G0 = tanh_(vg0), o0 = sigf(vo0);
      float i1 = sigf(vi1), f1 = sigf(vf1), G1 = tanh_(vg1), o1 = sigf(vo1);
      c0 = f0*c0 + i0*G0;
      c1 = f1*c1 + i1*G1;
      float h0 = o0*tanh_(c0);
      float h1 = o1*tanh_(c1);
      hold = (unsigned int)f2h(h0) | ((unsigned int)f2h(h1) << 16);
      if (LAYER == 0) {
        *(unsigned int*)(g_out1 + ((size_t)myseq*T_ + pos)*1024 + dir*H_ + col0 + hcA) = hold;
      } else {
        g_hlast[dir][myseq*H_ + col0 + hcA]     = h0;
        g_hlast[dir][myseq*H_ + col0 + hcA + 1] = h1;
      }
    }
    // always publish current h (held value for finished sequences)
    *(unsigned int*)(hwrite + myseq*H_ + col0 + hcA) = hold;

    // ---- barrier among this direction's 64 WGs (cross-XCD safe) ----
    __syncthreads();                     // all of this WG's work for step s is done
    if (tid == 0) {
      __threadfence();                   // agent release
      unsigned int prev = __hip_atomic_fetch_add(cnt_sub, 1u, __ATOMIC_ACQ_REL, __HIP_MEMORY_SCOPE_AGENT);
      if ((prev & 7u) == 7u)
        __hip_atomic_fetch_add(cnt_root, 1u, __ATOMIC_ACQ_REL, __HIP_MEMORY_SCOPE_AGENT);
      const unsigned int tgt = 8u*(unsigned int)(s + 1);
      while (__hip_atomic_load(cnt_root, __ATOMIC_ACQUIRE, __HIP_MEMORY_SCOPE_AGENT) < tgt)
        __builtin_amdgcn_s_sleep(1);
      __threadfence();                   // agent acquire
    }
    __syncthreads();
  }
}

// ---------------- final projection: out[b] = sigmoid([h_f|h_b]·w_out + b_out) --------
__global__ void k_final(const float* __restrict__ w_out, const float* __restrict__ b_out,
                        float* __restrict__ out) {
  const int b = blockIdx.x;
  const int tid = threadIdx.x;
  float sum = 0.f;
  for (int k = tid; k < 1024; k += 256) {
    float h = (k < 512) ? g_hlast[0][b*H_ + k] : g_hlast[1][b*H_ + k - 512];
    sum += h * w_out[k];
  }
  __shared__ float red[256];
  red[tid] = sum;
  __syncthreads();
  for (int st = 128; st > 0; st >>= 1) {
    if (tid < st) red[tid] += red[tid + st];
    __syncthreads();
  }
  if (tid == 0) out[b] = 1.f/(1.f + __expf(-(red[0] + b_out[0])));
}

// ---------------- launch ----------------
extern "C" void kernel_launch(void* const* d_in, const int* in_sizes, int n_in,
                              void* d_out, int out_size, void* d_ws, size_t ws_size,
                              hipStream_t stream) {
  (void)in_sizes; (void)n_in; (void)d_ws; (void)ws_size; (void)out_size;
  const float* seqs    = (const float*)d_in[0];
  const int*   lens    = (const int*)d_in[1];     // int32! ("integer -> const int*")
  const float* w_ih_l0 = (const float*)d_in[2];
  const float* w_hh_l0 = (const float*)d_in[3];
  const float* b_ih_l0 = (const float*)d_in[4];
  const float* b_hh_l0 = (const float*)d_in[5];
  const float* w_ih_l1 = (const float*)d_in[6];
  const float* w_hh_l1 = (const float*)d_in[7];
  const float* b_ih_l1 = (const float*)d_in[8];
  const float* b_hh_l1 = (const float*)d_in[9];
  const float* w_out   = (const float*)d_in[10];
  const float* b_out   = (const float*)d_in[11];
  float* outp = (float*)d_out;

  hipLaunchKernelGGL(k_init,   dim3(256),  dim3(256), 0, stream);
  hipLaunchKernelGGL(k_cvt_x,  dim3(2048), dim3(256), 0, stream, seqs);
  hipLaunchKernelGGL(k_cvt_w1, dim3(256),  dim3(256), 0, stream, w_ih_l0);
  hipLaunchKernelGGL(k_cvt_w2, dim3(512),  dim3(256), 0, stream, w_ih_l1);

  hipLaunchKernelGGL((k_xproj<0>), dim3(BT_/128, 16, 2), dim3(256), 0, stream,
                     b_ih_l0, b_hh_l0, lens);
  {
    void* args[] = { (void*)&w_hh_l0, (void*)&lens };
    hipError_t e = hipLaunchCooperativeKernel(k_scan<0>, dim3(128), dim3(256), args, 0u, stream);
    (void)e;
  }
  hipLaunchKernelGGL((k_xproj<1>), dim3(BT_/128, 16, 2), dim3(256), 0, stream,
                     b_ih_l1, b_hh_l1, lens);
  {
    void* args[] = { (void*)&w_hh_l1, (void*)&lens };
    hipError_t e = hipLaunchCooperativeKernel(k_scan<1>, dim3(128), dim3(256), args, 0u, stream);
    (void)e;
  }
  hipLaunchKernelGGL(k_final, dim3(64), dim3(256), 0, stream, w_out, b_out, outp);
}

// Round 6
// 29000.803 us; speedup vs baseline: 1.9904x; 1.9904x over previous
//
#include <hip/hip_runtime.h>
#include <stdint.h>
#include <stddef.h>

#define B_  64
#define T_  2048
#define XD  256
#define H_  512
#define G4  2048          // 4*H
#define BT_ (B_*T_)       // 131072

typedef __attribute__((ext_vector_type(8))) _Float16 f16x8;
typedef __attribute__((ext_vector_type(4))) float f32x4;
typedef __attribute__((ext_vector_type(4))) unsigned int u32x4;
typedef __attribute__((ext_vector_type(4))) unsigned short us4;
typedef __attribute__((ext_vector_type(2))) _Float16 f16x2;

// ---------------- static device scratch (total ~1.42 GB, must stay < 2 GiB for PC32 reloc) ----
__device__ __attribute__((aligned(256))) unsigned short g_xh[(size_t)BT_*XD];         // 67 MB  x in fp16
__device__ __attribute__((aligned(256))) unsigned short g_w1h[(size_t)2*G4*XD];       // 2 MB   w_ih_l0 fp16
__device__ __attribute__((aligned(256))) unsigned short g_w2h[(size_t)2*G4*1024];     // 8 MB   w_ih_l1 fp16
__device__ __attribute__((aligned(256))) _Float16       g_xproj[(size_t)2*BT_*G4];    // 1.07 GB [dir][b][t][2048] fp16
__device__ __attribute__((aligned(256))) unsigned short g_out1[(size_t)BT_*1024];     // 268 MB [b][t][fwd512|bwd512] fp16
__device__ __attribute__((aligned(256))) unsigned short g_hbuf[2][2][2][B_*H_];       // [layer][dir][pingpong] fp16
__device__ __attribute__((aligned(256))) float          g_hlast[2][B_*H_];            // layer2 final h (fp32)
__device__ unsigned int g_cnt_sub[2][2][8][32];   // [layer][dir][subgroup][pad]
__device__ unsigned int g_cnt_root[2][2][32];     // [layer][dir][pad]

__device__ inline unsigned short f2h(float f) {
  _Float16 h = (_Float16)f;            // v_cvt_f16_f32, RNE
  return __builtin_bit_cast(unsigned short, h);
}
__device__ inline float sigf(float x)  { return 1.f/(1.f + __expf(-x)); }
__device__ inline float tanh_(float x) { return 1.f - 2.f/(__expf(2.f*x) + 1.f); }

// ---------------- init: zero h buffers + barrier counters (every call) ----------------
__global__ void k_init() {
  unsigned int i = blockIdx.x*256u + threadIdx.x;
  unsigned int stride = gridDim.x*256u;
  unsigned int* hb = (unsigned int*)&g_hbuf[0][0][0][0];
  for (unsigned int j = i; j < sizeof(g_hbuf)/4; j += stride) hb[j] = 0u;
  unsigned int* cs = (unsigned int*)&g_cnt_sub[0][0][0][0];
  for (unsigned int j = i; j < sizeof(g_cnt_sub)/4; j += stride) cs[j] = 0u;
  unsigned int* cr = (unsigned int*)&g_cnt_root[0][0][0];
  for (unsigned int j = i; j < sizeof(g_cnt_root)/4; j += stride) cr[j] = 0u;
}

// ---------------- fp32 -> fp16 converts ----------------
__global__ void k_cvt_x(const float* __restrict__ src) {
  const size_t n4 = (size_t)BT_*XD/4;
  for (size_t j = (size_t)blockIdx.x*blockDim.x + threadIdx.x; j < n4;
       j += (size_t)gridDim.x*blockDim.x) {
    float4 v = ((const float4*)src)[j];
    us4 o = { f2h(v.x), f2h(v.y), f2h(v.z), f2h(v.w) };
    ((us4*)g_xh)[j] = o;
  }
}
__global__ void k_cvt_w1(const float* __restrict__ src) {
  const size_t n4 = (size_t)2*G4*XD/4;
  for (size_t j = (size_t)blockIdx.x*blockDim.x + threadIdx.x; j < n4;
       j += (size_t)gridDim.x*blockDim.x) {
    float4 v = ((const float4*)src)[j];
    us4 o = { f2h(v.x), f2h(v.y), f2h(v.z), f2h(v.w) };
    ((us4*)g_w1h)[j] = o;
  }
}
__global__ void k_cvt_w2(const float* __restrict__ src) {
  const size_t n4 = (size_t)2*G4*1024/4;
  for (size_t j = (size_t)blockIdx.x*blockDim.x + threadIdx.x; j < n4;
       j += (size_t)gridDim.x*blockDim.x) {
    float4 v = ((const float4*)src)[j];
    us4 o = { f2h(v.x), f2h(v.y), f2h(v.z), f2h(v.w) };
    ((us4*)g_w2h)[j] = o;
  }
}

// ---------------- x_proj GEMM: out[d][m][n] = A[m]·W[d][n] + b_ih[n] + b_hh[n] -------
// 128x128 tile, BK=64, 4 waves (each 64x64), XOR-swizzled LDS, fp16 MFMA 16x16x32.
template<int LAYER>
__global__ __launch_bounds__(256) void k_xproj(const float* __restrict__ b_ih,
                                               const float* __restrict__ b_hh,
                                               const int* __restrict__ lens) {
  constexpr int K = (LAYER == 0) ? XD : 1024;
  const unsigned short* __restrict__ Abf = (LAYER == 0) ? g_xh : g_out1;
  const unsigned short* __restrict__ Wbf = (LAYER == 0) ? g_w1h : g_w2h;

  const int m0 = blockIdx.x*128;
  const int n0 = blockIdx.y*128;
  const int d  = blockIdx.z;
  const int bseq = m0 / T_;
  const int t0   = m0 % T_;
  if (t0 >= lens[bseq]) return;   // whole tile past this sequence's length

  __shared__ unsigned short As[128*64];
  __shared__ unsigned short Bs[128*64];

  const int tid  = threadIdx.x;
  const int lane = tid & 63;
  const int wv   = tid >> 6;
  const int moff = (wv >> 1)*64;
  const int noff = (wv & 1)*64;

  f32x4 acc[4][4] = {};

  const unsigned short* Ag = Abf + (size_t)m0*K;
  const unsigned short* Wg = Wbf + ((size_t)d*G4 + n0)*K;

  for (int k0 = 0; k0 < K; k0 += 64) {
    __syncthreads();
    #pragma unroll
    for (int p = 0; p < 4; ++p) {
      int sidx = p*256 + tid;
      int row = sidx >> 3;
      int ch  = sidx & 7;
      u32x4 va = *(const u32x4*)(Ag + (size_t)row*K + k0 + ch*8);
      u32x4 vb = *(const u32x4*)(Wg + (size_t)row*K + k0 + ch*8);
      int wb = row*128 + ((ch ^ (row & 7)) << 4);
      *(u32x4*)((char*)As + wb) = va;
      *(u32x4*)((char*)Bs + wb) = vb;
    }
    __syncthreads();
    #pragma unroll
    for (int kt = 0; kt < 2; ++kt) {
      int slot = kt*4 + (lane >> 4);
      f16x8 af[4], bfv[4];
      #pragma unroll
      for (int mt = 0; mt < 4; ++mt) {
        int r = moff + mt*16 + (lane & 15);
        af[mt] = *(const f16x8*)((const char*)As + r*128 + ((slot ^ (r & 7)) << 4));
      }
      #pragma unroll
      for (int nt = 0; nt < 4; ++nt) {
        int r = noff + nt*16 + (lane & 15);
        bfv[nt] = *(const f16x8*)((const char*)Bs + r*128 + ((slot ^ (r & 7)) << 4));
      }
      #pragma unroll
      for (int mt = 0; mt < 4; ++mt)
        #pragma unroll
        for (int nt = 0; nt < 4; ++nt)
          acc[mt][nt] = __builtin_amdgcn_mfma_f32_16x16x32_f16(af[mt], bfv[nt], acc[mt][nt], 0, 0, 0);
    }
  }

  #pragma unroll
  for (int nt = 0; nt < 4; ++nt) {
    const int col = n0 + noff + nt*16 + (lane & 15);
    const float bias = b_ih[d*G4 + col] + b_hh[d*G4 + col];
    #pragma unroll
    for (int mt = 0; mt < 4; ++mt) {
      const int row = m0 + moff + mt*16 + (lane >> 4)*4;
      _Float16* op = g_xproj + ((size_t)d*BT_ + row)*G4 + col;
      #pragma unroll
      for (int j = 0; j < 4; ++j)
        op[(size_t)j*G4] = (_Float16)(acc[mt][nt][j] + bias);
    }
  }
}

// ---------------- recurrent scan ----------------
// grid = 128 blocks: dir = bid&1, wg = bid>>1 (64 WGs per direction).
// WG wg owns h-columns [wg*8, wg*8+8) i.e. gate columns {g*512 + wg*8 + j}.
// h exchange via agent-scope relaxed atomics (sc1 ops at the coherent LLC) — NO
// threadfence: avoids per-step buffer_wbl2 (full L2 writeback) + buffer_inv.
// Ordering: __syncthreads' per-wave vmcnt(0) drain completes bypassing stores at
// the LLC before tid0's relaxed counter increment; readers bypass L1/L2 so they
// observe LLC data with no invalidate.
template<int LAYER>
__global__ __launch_bounds__(256) void k_scan(const float* __restrict__ w_hh,
                                              const int* __restrict__ lens) {
  const int dir  = blockIdx.x & 1;
  const int wg   = blockIdx.x >> 1;
  const int tid  = threadIdx.x;
  const int lane = tid & 63;
  const int wv   = tid >> 6;

  __shared__ unsigned short Wl[32*512];   // 32 KB, XOR-swizzled, rows = 32 gate cols (fp16)
  __shared__ float gs[64*33];             // gate scratch, padded stride 33

  // load + convert this WG's W_hh slice (rows: gate*512 + wg*8 + hc)
  for (int i = tid; i < 32*256; i += 256) {
    int e = i*2;
    int row = e >> 9;
    int k   = e & 511;
    int gate = row >> 3, hc = row & 7;
    int grow = gate*H_ + wg*8 + hc;
    const float* wsrc = w_hh + ((size_t)dir*G4 + grow)*H_ + k;
    unsigned int pk = (unsigned int)f2h(wsrc[0]) | ((unsigned int)f2h(wsrc[1]) << 16);
    int byte = row*1024 + ((((k*2) >> 4) ^ (row & 7)) << 4) + ((k*2) & 15);
    *(unsigned int*)((char*)Wl + byte) = pk;
  }

  const int myseq = tid >> 2;            // thread owns (myseq, hcA) and (myseq, hcA+1)
  const int hcA   = (tid & 3)*2;
  const int mylen = lens[myseq];         // int32 input
  const int maxlen = lens[0];            // sorted descending
  const int col0  = wg*8;
  const int arow  = wv*16 + (lane & 15);
  const int koff  = (lane >> 4)*8;       // halves
  float c0 = 0.f, c1 = 0.f;
  unsigned int hold = 0u;                // packed fp16 pair, current h for my items

  unsigned short* hbuf0 = &g_hbuf[LAYER][dir][0][0];
  unsigned short* hbuf1 = &g_hbuf[LAYER][dir][1][0];
  unsigned int* cnt_sub  = &g_cnt_sub[LAYER][dir][wg >> 3][0];
  unsigned int* cnt_root = &g_cnt_root[LAYER][dir][0];

  __syncthreads();

  for (int s = 0; s < maxlen; ++s) {
    const unsigned short* hread = (s & 1) ? hbuf1 : hbuf0;
    unsigned short* hwrite      = (s & 1) ? hbuf0 : hbuf1;
    const bool act = s < mylen;
    const int pos  = dir ? (mylen - 1 - s) : s;

    float xg[8];
    if (act) {
      const unsigned int* xp32 = (const unsigned int*)
          (g_xproj + (((size_t)dir*B_ + myseq)*T_ + pos)*G4 + col0);
      #pragma unroll
      for (int g = 0; g < 4; ++g) {
        unsigned int pk = xp32[g*(H_/2) + (hcA >> 1)];
        f16x2 p = __builtin_bit_cast(f16x2, pk);
        xg[2*g]   = (float)p[0];
        xg[2*g+1] = (float)p[1];
      }
    }

    // recurrent GEMM: wave wv computes seqs [16wv,16wv+16) x 32 gate cols.
    // A-fragments read with agent-scope relaxed atomics (bypass stale L1/L2).
    const unsigned long long* hr = (const unsigned long long*)(hread + (size_t)arow*H_);
    f32x4 acc0 = {0.f,0.f,0.f,0.f};
    f32x4 acc1 = {0.f,0.f,0.f,0.f};
    #pragma unroll
    for (int kt = 0; kt < 16; ++kt) {
      int idx = (kt*32 + koff) >> 2;     // in 8B units
      unsigned long long q0 = __hip_atomic_load(hr + idx,     __ATOMIC_RELAXED, __HIP_MEMORY_SCOPE_AGENT);
      unsigned long long q1 = __hip_atomic_load(hr + idx + 1, __ATOMIC_RELAXED, __HIP_MEMORY_SCOPE_AGENT);
      union { unsigned long long q[2]; f16x8 v; } u;
      u.q[0] = q0; u.q[1] = q1;
      f16x8 a = u.v;
      int slot = kt*4 + (lane >> 4);
      int r0 = lane & 15;
      int r1 = 16 + r0;
      f16x8 b0 = *(const f16x8*)((const char*)Wl + r0*1024 + ((slot ^ (r0 & 7)) << 4));
      f16x8 b1 = *(const f16x8*)((const char*)Wl + r1*1024 + ((slot ^ (r1 & 7)) << 4));
      acc0 = __builtin_amdgcn_mfma_f32_16x16x32_f16(a, b0, acc0, 0, 0, 0);
      acc1 = __builtin_amdgcn_mfma_f32_16x16x32_f16(a, b1, acc1, 0, 0, 0);
    }
    #pragma unroll
    for (int j = 0; j < 4; ++j) {
      int srow = wv*16 + (lane >> 4)*4 + j;
      gs[srow*33 + (lane & 15)]      = acc0[j];
      gs[srow*33 + 16 + (lane & 15)] = acc1[j];
    }
    // gs producer lanes and consumer lanes are in the SAME wave -> in-order DS ops.
    if (act) {
      const int q = myseq*33;
      float vi0 = gs[q + hcA]        + xg[0];
      float vi1 = gs[q + hcA + 1]    + xg[1];
      float vf0 = gs[q + 8 + hcA]    + xg[2];
      float vf1 = gs[q + 8 + hcA + 1]+ xg[3];
      float vg0 = gs[q + 16 + hcA]   + xg[4];
      float vg1 = gs[q + 16 + hcA+1] + xg[5];
      float vo0 = gs[q + 24 + hcA]   + xg[6];
      float vo1 = gs[q + 24 + hcA+1] + xg[7];
      float i0 = sigf(vi0), f0 = sigf(vf0), G0 = tanh_(vg0), o0 = sigf(vo0);
      float i1 = sigf(vi1), f1 = sigf(vf1), G1 = tanh_(vg1), o1 = sigf(vo1);
      c0 = f0*c0 + i0*G0;
      c1 = f1*c1 + i1*G1;
      float h0 = o0*tanh_(c0);
      float h1 = o1*tanh_(c1);
      hold = (unsigned int)f2h(h0) | ((unsigned int)f2h(h1) << 16);
      if (LAYER == 0) {
        *(unsigned int*)(g_out1 + ((size_t)myseq*T_ + pos)*1024 + dir*H_ + col0 + hcA) = hold;
      } else {
        g_hlast[dir][myseq*H_ + col0 + hcA]     = h0;
        g_hlast[dir][myseq*H_ + col0 + hcA + 1] = h1;
      }
    }
    // publish current h (held value for finished sequences) — bypassing store
    __hip_atomic_store((unsigned int*)(hwrite + myseq*H_ + col0 + hcA), hold,
                       __ATOMIC_RELAXED, __HIP_MEMORY_SCOPE_AGENT);

    // ---- barrier among this direction's 64 WGs (relaxed, no cache maintenance) ----
    __syncthreads();                     // per-wave vmcnt(0) drain: bypass stores at LLC
    if (tid == 0) {
      unsigned int prev = __hip_atomic_fetch_add(cnt_sub, 1u, __ATOMIC_RELAXED, __HIP_MEMORY_SCOPE_AGENT);
      if ((prev & 7u) == 7u)
        __hip_atomic_fetch_add(cnt_root, 1u, __ATOMIC_RELAXED, __HIP_MEMORY_SCOPE_AGENT);
      const unsigned int tgt = 8u*(unsigned int)(s + 1);
      while (__hip_atomic_load(cnt_root, __ATOMIC_RELAXED, __HIP_MEMORY_SCOPE_AGENT) < tgt)
        __builtin_amdgcn_s_sleep(1);
    }
    __syncthreads();
  }
}

// ---------------- final projection: out[b] = sigmoid([h_f|h_b]·w_out + b_out) --------
__global__ void k_final(const float* __restrict__ w_out, const float* __restrict__ b_out,
                        float* __restrict__ out) {
  const int b = blockIdx.x;
  const int tid = threadIdx.x;
  float sum = 0.f;
  for (int k = tid; k < 1024; k += 256) {
    float h = (k < 512) ? g_hlast[0][b*H_ + k] : g_hlast[1][b*H_ + k - 512];
    sum += h * w_out[k];
  }
  __shared__ float red[256];
  red[tid] = sum;
  __syncthreads();
  for (int st = 128; st > 0; st >>= 1) {
    if (tid < st) red[tid] += red[tid + st];
    __syncthreads();
  }
  if (tid == 0) out[b] = 1.f/(1.f + __expf(-(red[0] + b_out[0])));
}

// ---------------- launch ----------------
extern "C" void kernel_launch(void* const* d_in, const int* in_sizes, int n_in,
                              void* d_out, int out_size, void* d_ws, size_t ws_size,
                              hipStream_t stream) {
  (void)in_sizes; (void)n_in; (void)d_ws; (void)ws_size; (void)out_size;
  const float* seqs    = (const float*)d_in[0];
  const int*   lens    = (const int*)d_in[1];     // int32 ("integer -> const int*")
  const float* w_ih_l0 = (const float*)d_in[2];
  const float* w_hh_l0 = (const float*)d_in[3];
  const float* b_ih_l0 = (const float*)d_in[4];
  const float* b_hh_l0 = (const float*)d_in[5];
  const float* w_ih_l1 = (const float*)d_in[6];
  const float* w_hh_l1 = (const float*)d_in[7];
  const float* b_ih_l1 = (const float*)d_in[8];
  const float* b_hh_l1 = (const float*)d_in[9];
  const float* w_out   = (const float*)d_in[10];
  const float* b_out   = (const float*)d_in[11];
  float* outp = (float*)d_out;

  hipLaunchKernelGGL(k_init,   dim3(256),  dim3(256), 0, stream);
  hipLaunchKernelGGL(k_cvt_x,  dim3(2048), dim3(256), 0, stream, seqs);
  hipLaunchKernelGGL(k_cvt_w1, dim3(256),  dim3(256), 0, stream, w_ih_l0);
  hipLaunchKernelGGL(k_cvt_w2, dim3(512),  dim3(256), 0, stream, w_ih_l1);

  hipLaunchKernelGGL((k_xproj<0>), dim3(BT_/128, 16, 2), dim3(256), 0, stream,
                     b_ih_l0, b_hh_l0, lens);
  {
    void* args[] = { (void*)&w_hh_l0, (void*)&lens };
    hipError_t e = hipLaunchCooperativeKernel(k_scan<0>, dim3(128), dim3(256), args, 0u, stream);
    (void)e;
  }
  hipLaunchKernelGGL((k_xproj<1>), dim3(BT_/128, 16, 2), dim3(256), 0, stream,
                     b_ih_l1, b_hh_l1, lens);
  {
    void* args[] = { (void*)&w_hh_l1, (void*)&lens };
    hipError_t e = hipLaunchCooperativeKernel(k_scan<1>, dim3(128), dim3(256), args, 0u, stream);
    (void)e;
  }
  hipLaunchKernelGGL(k_final, dim3(64), dim3(256), 0, stream, w_out, b_out, outp);
}

// Round 7
// 23780.673 us; speedup vs baseline: 2.4273x; 1.2195x over previous
//
#include <hip/hip_runtime.h>
#include <stdint.h>
#include <stddef.h>

#define B_  64
#define T_  2048
#define XD  256
#define H_  512
#define G4  2048          // 4*H
#define BT_ (B_*T_)       // 131072

typedef __attribute__((ext_vector_type(8))) _Float16 f16x8;
typedef __attribute__((ext_vector_type(4))) float f32x4;
typedef __attribute__((ext_vector_type(4))) unsigned int u32x4;
typedef __attribute__((ext_vector_type(4))) unsigned short us4;
typedef __attribute__((ext_vector_type(2))) _Float16 f16x2;

// ---------------- static device scratch (total ~1.42 GB < 2 GiB PC32-reloc budget) ----
__device__ __attribute__((aligned(256))) unsigned short g_xh[(size_t)BT_*XD];         // x fp16
__device__ __attribute__((aligned(256))) unsigned short g_w1h[(size_t)2*G4*XD];       // w_ih_l0 fp16
__device__ __attribute__((aligned(256))) unsigned short g_w2h[(size_t)2*G4*1024];     // w_ih_l1 fp16
__device__ __attribute__((aligned(256))) _Float16       g_xproj[(size_t)2*BT_*G4];    // 1.07 GB fp16
__device__ __attribute__((aligned(256))) unsigned short g_out1[(size_t)BT_*1024];     // 268 MB fp16
__device__ __attribute__((aligned(256))) unsigned short g_hbuf[2][2][2][B_*H_];       // [layer][dir][pp] fp16
__device__ __attribute__((aligned(256))) float          g_hlast[2][B_*H_];            // layer2 final h
__device__ __attribute__((aligned(256))) unsigned int   g_flag[2][2][64];             // [layer][dir][wg]

__device__ inline unsigned short f2h(float f) {
  _Float16 h = (_Float16)f;
  return __builtin_bit_cast(unsigned short, h);
}
__device__ inline float sigf(float x)  { return 1.f/(1.f + __expf(-x)); }
__device__ inline float tanh_(float x) { return 1.f - 2.f/(__expf(2.f*x) + 1.f); }

// bypass (coherent-point) 16B load / 4B store
__device__ inline f16x8 llc_ld16(const void* p) {
  f16x8 r;
  asm volatile("global_load_dwordx4 %0, %1, off sc0 sc1" : "=v"(r) : "v"(p) : "memory");
  return r;
}
__device__ inline void llc_st4(void* p, unsigned int v) {
  asm volatile("global_store_dword %0, %1, off sc0 sc1" :: "v"(p), "v"(v) : "memory");
}

// ---------------- init: zero h buffers + flags (every call) ----------------
__global__ void k_init() {
  unsigned int i = blockIdx.x*256u + threadIdx.x;
  unsigned int stride = gridDim.x*256u;
  unsigned int* hb = (unsigned int*)&g_hbuf[0][0][0][0];
  for (unsigned int j = i; j < sizeof(g_hbuf)/4; j += stride) hb[j] = 0u;
  unsigned int* fl = (unsigned int*)&g_flag[0][0][0];
  for (unsigned int j = i; j < sizeof(g_flag)/4; j += stride) fl[j] = 0u;
}

// ---------------- fp32 -> fp16 converts ----------------
__global__ void k_cvt_x(const float* __restrict__ src) {
  const size_t n4 = (size_t)BT_*XD/4;
  for (size_t j = (size_t)blockIdx.x*blockDim.x + threadIdx.x; j < n4;
       j += (size_t)gridDim.x*blockDim.x) {
    float4 v = ((const float4*)src)[j];
    us4 o = { f2h(v.x), f2h(v.y), f2h(v.z), f2h(v.w) };
    ((us4*)g_xh)[j] = o;
  }
}
__global__ void k_cvt_w1(const float* __restrict__ src) {
  const size_t n4 = (size_t)2*G4*XD/4;
  for (size_t j = (size_t)blockIdx.x*blockDim.x + threadIdx.x; j < n4;
       j += (size_t)gridDim.x*blockDim.x) {
    float4 v = ((const float4*)src)[j];
    us4 o = { f2h(v.x), f2h(v.y), f2h(v.z), f2h(v.w) };
    ((us4*)g_w1h)[j] = o;
  }
}
__global__ void k_cvt_w2(const float* __restrict__ src) {
  const size_t n4 = (size_t)2*G4*1024/4;
  for (size_t j = (size_t)blockIdx.x*blockDim.x + threadIdx.x; j < n4;
       j += (size_t)gridDim.x*blockDim.x) {
    float4 v = ((const float4*)src)[j];
    us4 o = { f2h(v.x), f2h(v.y), f2h(v.z), f2h(v.w) };
    ((us4*)g_w2h)[j] = o;
  }
}

// ---------------- x_proj GEMM (unchanged from r5) ----------------
template<int LAYER>
__global__ __launch_bounds__(256) void k_xproj(const float* __restrict__ b_ih,
                                               const float* __restrict__ b_hh,
                                               const int* __restrict__ lens) {
  constexpr int K = (LAYER == 0) ? XD : 1024;
  const unsigned short* __restrict__ Abf = (LAYER == 0) ? g_xh : g_out1;
  const unsigned short* __restrict__ Wbf = (LAYER == 0) ? g_w1h : g_w2h;

  const int m0 = blockIdx.x*128;
  const int n0 = blockIdx.y*128;
  const int d  = blockIdx.z;
  const int bseq = m0 / T_;
  const int t0   = m0 % T_;
  if (t0 >= lens[bseq]) return;

  __shared__ unsigned short As[128*64];
  __shared__ unsigned short Bs[128*64];

  const int tid  = threadIdx.x;
  const int lane = tid & 63;
  const int wv   = tid >> 6;
  const int moff = (wv >> 1)*64;
  const int noff = (wv & 1)*64;

  f32x4 acc[4][4] = {};

  const unsigned short* Ag = Abf + (size_t)m0*K;
  const unsigned short* Wg = Wbf + ((size_t)d*G4 + n0)*K;

  for (int k0 = 0; k0 < K; k0 += 64) {
    __syncthreads();
    #pragma unroll
    for (int p = 0; p < 4; ++p) {
      int sidx = p*256 + tid;
      int row = sidx >> 3;
      int ch  = sidx & 7;
      u32x4 va = *(const u32x4*)(Ag + (size_t)row*K + k0 + ch*8);
      u32x4 vb = *(const u32x4*)(Wg + (size_t)row*K + k0 + ch*8);
      int wb = row*128 + ((ch ^ (row & 7)) << 4);
      *(u32x4*)((char*)As + wb) = va;
      *(u32x4*)((char*)Bs + wb) = vb;
    }
    __syncthreads();
    #pragma unroll
    for (int kt = 0; kt < 2; ++kt) {
      int slot = kt*4 + (lane >> 4);
      f16x8 af[4], bfv[4];
      #pragma unroll
      for (int mt = 0; mt < 4; ++mt) {
        int r = moff + mt*16 + (lane & 15);
        af[mt] = *(const f16x8*)((const char*)As + r*128 + ((slot ^ (r & 7)) << 4));
      }
      #pragma unroll
      for (int nt = 0; nt < 4; ++nt) {
        int r = noff + nt*16 + (lane & 15);
        bfv[nt] = *(const f16x8*)((const char*)Bs + r*128 + ((slot ^ (r & 7)) << 4));
      }
      #pragma unroll
      for (int mt = 0; mt < 4; ++mt)
        #pragma unroll
        for (int nt = 0; nt < 4; ++nt)
          acc[mt][nt] = __builtin_amdgcn_mfma_f32_16x16x32_f16(af[mt], bfv[nt], acc[mt][nt], 0, 0, 0);
    }
  }

  #pragma unroll
  for (int nt = 0; nt < 4; ++nt) {
    const int col = n0 + noff + nt*16 + (lane & 15);
    const float bias = b_ih[d*G4 + col] + b_hh[d*G4 + col];
    #pragma unroll
    for (int mt = 0; mt < 4; ++mt) {
      const int row = m0 + moff + mt*16 + (lane >> 4)*4;
      _Float16* op = g_xproj + ((size_t)d*BT_ + row)*G4 + col;
      #pragma unroll
      for (int j = 0; j < 4; ++j)
        op[(size_t)j*G4] = (_Float16)(acc[mt][nt][j] + bias);
    }
  }
}

// ---------------- recurrent scan ----------------
// 128 blocks: dir=bid&1, wg=bid>>1. WG owns h-cols [wg*8,wg*8+8).
// Critical path per step: flag-observe -> batched bypass h-load (1 RT) ->
// MFMA(reg W) -> gates -> bypass h-store -> vmcnt drain -> s_barrier ->
// flag store -> remote poll. xg prefetched one step ahead (hidden).
template<int LAYER>
__global__ __launch_bounds__(256, 1) void k_scan(const float* __restrict__ w_hh,
                                                 const int* __restrict__ lens) {
  const int dir  = blockIdx.x & 1;
  const int wg   = blockIdx.x >> 1;
  const int tid  = threadIdx.x;
  const int lane = tid & 63;
  const int wv   = tid >> 6;

  __shared__ unsigned short Wl[32*512];   // 32 KB, XOR-swizzled
  __shared__ float gs[64*33];             // gate scratch

  for (int i = tid; i < 32*256; i += 256) {
    int e = i*2;
    int row = e >> 9;
    int k   = e & 511;
    int gate = row >> 3, hc = row & 7;
    int grow = gate*H_ + wg*8 + hc;
    const float* wsrc = w_hh + ((size_t)dir*G4 + grow)*H_ + k;
    unsigned int pk = (unsigned int)f2h(wsrc[0]) | ((unsigned int)f2h(wsrc[1]) << 16);
    int byte = row*1024 + ((((k*2) >> 4) ^ (row & 7)) << 4) + ((k*2) & 15);
    *(unsigned int*)((char*)Wl + byte) = pk;
  }
  __syncthreads();

  // preload W fragments into registers (static indexing -> stays in VGPRs)
  f16x8 b0r[16], b1r[16];
  {
    const int r0 = lane & 15, r1 = 16 + (lane & 15);
    #pragma unroll
    for (int kt = 0; kt < 16; ++kt) {
      int slot = kt*4 + (lane >> 4);
      b0r[kt] = *(const f16x8*)((const char*)Wl + r0*1024 + ((slot ^ (r0 & 7)) << 4));
      b1r[kt] = *(const f16x8*)((const char*)Wl + r1*1024 + ((slot ^ (r1 & 7)) << 4));
    }
  }

  const int myseq = tid >> 2;
  const int hcA   = (tid & 3)*2;
  const int mylen = lens[myseq];
  const int maxlen = lens[0];
  const int col0  = wg*8;
  const int arow  = wv*16 + (lane & 15);
  float c0 = 0.f, c1 = 0.f;
  float h0k = 0.f, h1k = 0.f;
  unsigned int hold = 0u;

  unsigned short* hbuf0 = &g_hbuf[LAYER][dir][0][0];
  unsigned short* hbuf1 = &g_hbuf[LAYER][dir][1][0];
  unsigned int*   flags = &g_flag[LAYER][dir][0];

  const unsigned int* xbase = (const unsigned int*)
      (g_xproj + (((size_t)dir*B_ + myseq)*T_)*G4 + col0) + (hcA >> 1);

  // prologue: prefetch xg for s=0 (clamped positions are always valid)
  unsigned int r0w, r1w, r2w, r3w;
  {
    int p0 = dir ? (mylen - 1) : 0;
    const unsigned int* xp = xbase + (size_t)p0*(G4/2);
    r0w = xp[0]; r1w = xp[256]; r2w = xp[512]; r3w = xp[768];
  }

  for (int s = 0; s < maxlen; ++s) {
    const unsigned short* hread = (s & 1) ? hbuf1 : hbuf0;
    unsigned short* hwrite      = (s & 1) ? hbuf0 : hbuf1;
    const bool act = s < mylen;

    // ---- 1. batched bypass h-load: 16 x dwordx4, one waitcnt ----
    const char* hb = (const char*)hread + arow*1024 + ((lane >> 4)*16);
    f16x8 aa[16];
    #pragma unroll
    for (int kt = 0; kt < 16; ++kt)
      aa[kt] = llc_ld16(hb + kt*64);
    asm volatile("s_waitcnt vmcnt(0)" ::: "memory");
    __builtin_amdgcn_sched_barrier(0);

    // ---- 1b. prefetch xg for s+1 (hidden under compute + barrier) ----
    unsigned int n0w, n1w, n2w, n3w;
    {
      int s1 = s + 1;
      int p1 = dir ? (mylen - 1 - s1) : s1;
      p1 = p1 < 0 ? 0 : (p1 > mylen - 1 ? mylen - 1 : p1);
      const unsigned int* xp = xbase + (size_t)p1*(G4/2);
      n0w = xp[0]; n1w = xp[256]; n2w = xp[512]; n3w = xp[768];
    }

    // ---- 2. recurrent MFMA (W in regs) ----
    f32x4 acc0 = {0.f,0.f,0.f,0.f};
    f32x4 acc1 = {0.f,0.f,0.f,0.f};
    #pragma unroll
    for (int kt = 0; kt < 16; ++kt) {
      acc0 = __builtin_amdgcn_mfma_f32_16x16x32_f16(aa[kt], b0r[kt], acc0, 0, 0, 0);
      acc1 = __builtin_amdgcn_mfma_f32_16x16x32_f16(aa[kt], b1r[kt], acc1, 0, 0, 0);
    }

    // ---- 3. same-wave LDS transpose ----
    #pragma unroll
    for (int j = 0; j < 4; ++j) {
      int srow = wv*16 + (lane >> 4)*4 + j;
      gs[srow*33 + (lane & 15)]      = acc0[j];
      gs[srow*33 + 16 + (lane & 15)] = acc1[j];
    }

    // ---- 4. gates (xg from prefetched regs) ----
    {
      f16x2 p0 = __builtin_bit_cast(f16x2, r0w);
      f16x2 p1 = __builtin_bit_cast(f16x2, r1w);
      f16x2 p2 = __builtin_bit_cast(f16x2, r2w);
      f16x2 p3 = __builtin_bit_cast(f16x2, r3w);
      const int q = myseq*33;
      float vi0 = gs[q + hcA]         + (float)p0[0];
      float vi1 = gs[q + hcA + 1]     + (float)p0[1];
      float vf0 = gs[q + 8 + hcA]     + (float)p1[0];
      float vf1 = gs[q + 8 + hcA + 1] + (float)p1[1];
      float vg0 = gs[q + 16 + hcA]    + (float)p2[0];
      float vg1 = gs[q + 16 + hcA+1]  + (float)p2[1];
      float vo0 = gs[q + 24 + hcA]    + (float)p3[0];
      float vo1 = gs[q + 24 + hcA+1]  + (float)p3[1];
      if (act) {
        float i0 = sigf(vi0), f0 = sigf(vf0), G0 = tanh_(vg0), o0 = sigf(vo0);
        float i1 = sigf(vi1), f1 = sigf(vf1), G1 = tanh_(vg1), o1 = sigf(vo1);
        c0 = f0*c0 + i0*G0;
        c1 = f1*c1 + i1*G1;
        h0k = o0*tanh_(c0);
        h1k = o1*tanh_(c1);
        hold = (unsigned int)f2h(h0k) | ((unsigned int)f2h(h1k) << 16);
      }
    }
    r0w = n0w; r1w = n1w; r2w = n2w; r3w = n3w;

    // ---- 5. stores (all unconditional/idempotent; clamped pos) ----
    {
      int pos = dir ? (mylen - 1 - s) : s;
      pos = pos < 0 ? 0 : (pos > mylen - 1 ? mylen - 1 : pos);
      if (LAYER == 0) {
        *(unsigned int*)(g_out1 + ((size_t)myseq*T_ + pos)*1024 + dir*H_ + col0 + hcA) = hold;
      } else {
        g_hlast[dir][myseq*H_ + col0 + hcA]     = h0k;
        g_hlast[dir][myseq*H_ + col0 + hcA + 1] = h1k;
      }
    }
    llc_st4(hwrite + myseq*H_ + col0 + hcA, hold);

    // ---- 6. drain own stores, intra-WG rendezvous ----
    asm volatile("s_waitcnt vmcnt(0)\n\ts_barrier" ::: "memory");

    // ---- 7. signal + poll (wave0) ----
    if (tid == 0) llc_st4(&flags[wg], (unsigned int)(s + 1));
    if (wv == 0) {
      const unsigned int tgt = (unsigned int)(s + 1);
      while (true) {
        unsigned int v = __hip_atomic_load(&flags[lane], __ATOMIC_RELAXED, __HIP_MEMORY_SCOPE_AGENT);
        if (__all(v >= tgt)) break;
        __builtin_amdgcn_s_sleep(1);
      }
    }
    asm volatile("s_barrier" ::: "memory");
  }
}

// ---------------- final projection ----------------
__global__ void k_final(const float* __restrict__ w_out, const float* __restrict__ b_out,
                        float* __restrict__ out) {
  const int b = blockIdx.x;
  const int tid = threadIdx.x;
  float sum = 0.f;
  for (int k = tid; k < 1024; k += 256) {
    float h = (k < 512) ? g_hlast[0][b*H_ + k] : g_hlast[1][b*H_ + k - 512];
    sum += h * w_out[k];
  }
  __shared__ float red[256];
  red[tid] = sum;
  __syncthreads();
  for (int st = 128; st > 0; st >>= 1) {
    if (tid < st) red[tid] += red[tid + st];
    __syncthreads();
  }
  if (tid == 0) out[b] = 1.f/(1.f + __expf(-(red[0] + b_out[0])));
}

// ---------------- launch ----------------
extern "C" void kernel_launch(void* const* d_in, const int* in_sizes, int n_in,
                              void* d_out, int out_size, void* d_ws, size_t ws_size,
                              hipStream_t stream) {
  (void)in_sizes; (void)n_in; (void)d_ws; (void)ws_size; (void)out_size;
  const float* seqs    = (const float*)d_in[0];
  const int*   lens    = (const int*)d_in[1];
  const float* w_ih_l0 = (const float*)d_in[2];
  const float* w_hh_l0 = (const float*)d_in[3];
  const float* b_ih_l0 = (const float*)d_in[4];
  const float* b_hh_l0 = (const float*)d_in[5];
  const float* w_ih_l1 = (const float*)d_in[6];
  const float* w_hh_l1 = (const float*)d_in[7];
  const float* b_ih_l1 = (const float*)d_in[8];
  const float* b_hh_l1 = (const float*)d_in[9];
  const float* w_out   = (const float*)d_in[10];
  const float* b_out   = (const float*)d_in[11];
  float* outp = (float*)d_out;

  hipLaunchKernelGGL(k_init,   dim3(256),  dim3(256), 0, stream);
  hipLaunchKernelGGL(k_cvt_x,  dim3(2048), dim3(256), 0, stream, seqs);
  hipLaunchKernelGGL(k_cvt_w1, dim3(256),  dim3(256), 0, stream, w_ih_l0);
  hipLaunchKernelGGL(k_cvt_w2, dim3(512),  dim3(256), 0, stream, w_ih_l1);

  hipLaunchKernelGGL((k_xproj<0>), dim3(BT_/128, 16, 2), dim3(256), 0, stream,
                     b_ih_l0, b_hh_l0, lens);
  {
    void* args[] = { (void*)&w_hh_l0, (void*)&lens };
    hipError_t e = hipLaunchCooperativeKernel(k_scan<0>, dim3(128), dim3(256), args, 0u, stream);
    (void)e;
  }
  hipLaunchKernelGGL((k_xproj<1>), dim3(BT_/128, 16, 2), dim3(256), 0, stream,
                     b_ih_l1, b_hh_l1, lens);
  {
    void* args[] = { (void*)&w_hh_l1, (void*)&lens };
    hipError_t e = hipLaunchCooperativeKernel(k_scan<1>, dim3(128), dim3(256), args, 0u, stream);
    (void)e;
  }
  hipLaunchKernelGGL(k_final, dim3(64), dim3(256), 0, stream, w_out, b_out, outp);
}

// Round 8
// 19156.816 us; speedup vs baseline: 3.0132x; 1.2414x over previous
//
#include <hip/hip_runtime.h>
#include <stdint.h>
#include <stddef.h>

#define B_  64
#define T_  2048
#define XD  256
#define H_  512
#define G4  2048          // 4*H
#define BT_ (B_*T_)       // 131072

typedef __attribute__((ext_vector_type(8))) _Float16 f16x8;
typedef __attribute__((ext_vector_type(4))) float f32x4;
typedef __attribute__((ext_vector_type(4))) unsigned int u32x4;
typedef __attribute__((ext_vector_type(4))) unsigned short us4;
typedef __attribute__((ext_vector_type(2))) _Float16 f16x2;

// ---------------- static device scratch (total ~1.42 GB < 2 GiB PC32-reloc budget) ----
__device__ __attribute__((aligned(256))) unsigned short g_xh[(size_t)BT_*XD];         // x fp16
__device__ __attribute__((aligned(256))) unsigned short g_w1h[(size_t)2*G4*XD];       // w_ih_l0 fp16
__device__ __attribute__((aligned(256))) unsigned short g_w2h[(size_t)2*G4*1024];     // w_ih_l1 fp16
__device__ __attribute__((aligned(256))) _Float16       g_xproj[(size_t)2*BT_*G4];    // 1.07 GB fp16
__device__ __attribute__((aligned(256))) unsigned short g_out1[(size_t)BT_*1024];     // 268 MB fp16
__device__ __attribute__((aligned(256))) unsigned short g_hbuf[2][2][2][B_*H_];       // [layer][dir][pp] fp16
__device__ __attribute__((aligned(256))) float          g_hlast[2][B_*H_];            // layer2 final h
__device__ __attribute__((aligned(256))) unsigned int   g_flag[2][2][64][32];         // [layer][dir][wg][pad128B]

__device__ inline unsigned short f2h(float f) {
  _Float16 h = (_Float16)f;
  return __builtin_bit_cast(unsigned short, h);
}
__device__ inline float sigf(float x)  { return 1.f/(1.f + __expf(-x)); }
__device__ inline float tanh_(float x) { return 1.f - 2.f/(__expf(2.f*x) + 1.f); }

// ---------------- init: zero h buffers + flags (every call) ----------------
__global__ void k_init() {
  unsigned int i = blockIdx.x*256u + threadIdx.x;
  unsigned int stride = gridDim.x*256u;
  unsigned int* hb = (unsigned int*)&g_hbuf[0][0][0][0];
  for (unsigned int j = i; j < sizeof(g_hbuf)/4; j += stride) hb[j] = 0u;
  unsigned int* fl = (unsigned int*)&g_flag[0][0][0][0];
  for (unsigned int j = i; j < sizeof(g_flag)/4; j += stride) fl[j] = 0u;
}

// ---------------- fp32 -> fp16 converts ----------------
__global__ void k_cvt_x(const float* __restrict__ src) {
  const size_t n4 = (size_t)BT_*XD/4;
  for (size_t j = (size_t)blockIdx.x*blockDim.x + threadIdx.x; j < n4;
       j += (size_t)gridDim.x*blockDim.x) {
    float4 v = ((const float4*)src)[j];
    us4 o = { f2h(v.x), f2h(v.y), f2h(v.z), f2h(v.w) };
    ((us4*)g_xh)[j] = o;
  }
}
__global__ void k_cvt_w1(const float* __restrict__ src) {
  const size_t n4 = (size_t)2*G4*XD/4;
  for (size_t j = (size_t)blockIdx.x*blockDim.x + threadIdx.x; j < n4;
       j += (size_t)gridDim.x*blockDim.x) {
    float4 v = ((const float4*)src)[j];
    us4 o = { f2h(v.x), f2h(v.y), f2h(v.z), f2h(v.w) };
    ((us4*)g_w1h)[j] = o;
  }
}
__global__ void k_cvt_w2(const float* __restrict__ src) {
  const size_t n4 = (size_t)2*G4*1024/4;
  for (size_t j = (size_t)blockIdx.x*blockDim.x + threadIdx.x; j < n4;
       j += (size_t)gridDim.x*blockDim.x) {
    float4 v = ((const float4*)src)[j];
    us4 o = { f2h(v.x), f2h(v.y), f2h(v.z), f2h(v.w) };
    ((us4*)g_w2h)[j] = o;
  }
}

// ---------------- x_proj GEMM (unchanged) ----------------
template<int LAYER>
__global__ __launch_bounds__(256) void k_xproj(const float* __restrict__ b_ih,
                                               const float* __restrict__ b_hh,
                                               const int* __restrict__ lens) {
  constexpr int K = (LAYER == 0) ? XD : 1024;
  const unsigned short* __restrict__ Abf = (LAYER == 0) ? g_xh : g_out1;
  const unsigned short* __restrict__ Wbf = (LAYER == 0) ? g_w1h : g_w2h;

  const int m0 = blockIdx.x*128;
  const int n0 = blockIdx.y*128;
  const int d  = blockIdx.z;
  const int bseq = m0 / T_;
  const int t0   = m0 % T_;
  if (t0 >= lens[bseq]) return;

  __shared__ unsigned short As[128*64];
  __shared__ unsigned short Bs[128*64];

  const int tid  = threadIdx.x;
  const int lane = tid & 63;
  const int wv   = tid >> 6;
  const int moff = (wv >> 1)*64;
  const int noff = (wv & 1)*64;

  f32x4 acc[4][4] = {};

  const unsigned short* Ag = Abf + (size_t)m0*K;
  const unsigned short* Wg = Wbf + ((size_t)d*G4 + n0)*K;

  for (int k0 = 0; k0 < K; k0 += 64) {
    __syncthreads();
    #pragma unroll
    for (int p = 0; p < 4; ++p) {
      int sidx = p*256 + tid;
      int row = sidx >> 3;
      int ch  = sidx & 7;
      u32x4 va = *(const u32x4*)(Ag + (size_t)row*K + k0 + ch*8);
      u32x4 vb = *(const u32x4*)(Wg + (size_t)row*K + k0 + ch*8);
      int wb = row*128 + ((ch ^ (row & 7)) << 4);
      *(u32x4*)((char*)As + wb) = va;
      *(u32x4*)((char*)Bs + wb) = vb;
    }
    __syncthreads();
    #pragma unroll
    for (int kt = 0; kt < 2; ++kt) {
      int slot = kt*4 + (lane >> 4);
      f16x8 af[4], bfv[4];
      #pragma unroll
      for (int mt = 0; mt < 4; ++mt) {
        int r = moff + mt*16 + (lane & 15);
        af[mt] = *(const f16x8*)((const char*)As + r*128 + ((slot ^ (r & 7)) << 4));
      }
      #pragma unroll
      for (int nt = 0; nt < 4; ++nt) {
        int r = noff + nt*16 + (lane & 15);
        bfv[nt] = *(const f16x8*)((const char*)Bs + r*128 + ((slot ^ (r & 7)) << 4));
      }
      #pragma unroll
      for (int mt = 0; mt < 4; ++mt)
        #pragma unroll
        for (int nt = 0; nt < 4; ++nt)
          acc[mt][nt] = __builtin_amdgcn_mfma_f32_16x16x32_f16(af[mt], bfv[nt], acc[mt][nt], 0, 0, 0);
    }
  }

  #pragma unroll
  for (int nt = 0; nt < 4; ++nt) {
    const int col = n0 + noff + nt*16 + (lane & 15);
    const float bias = b_ih[d*G4 + col] + b_hh[d*G4 + col];
    #pragma unroll
    for (int mt = 0; mt < 4; ++mt) {
      const int row = m0 + moff + mt*16 + (lane >> 4)*4;
      _Float16* op = g_xproj + ((size_t)d*BT_ + row)*G4 + col;
      #pragma unroll
      for (int j = 0; j < 4; ++j)
        op[(size_t)j*G4] = (_Float16)(acc[mt][nt][j] + bias);
    }
  }
}

// ---------------- recurrent scan ----------------
// 128 blocks: dir=bid&1, wg=bid>>1. WG owns h-cols [wg*8,wg*8+8).
// All cross-WG traffic at AGENT scope (sc1 only -> completes at the coherent LLC,
// not HBM). Chain: h-load(16x dwordx4, 1 waitcnt) -> MFMA(reg W, split chains) ->
// gates -> h-store sc1 -> vmcnt(0)+s_barrier -> flag store (128B-spaced) -> poll.
// xg prefetch issued after h-loads, excluded from the MFMA wait via vmcnt(4),
// drained by the store-drain (mostly overlapped).
template<int LAYER>
__global__ __launch_bounds__(256, 1) void k_scan(const float* __restrict__ w_hh,
                                                 const int* __restrict__ lens) {
  const int dir  = blockIdx.x & 1;
  const int wg   = blockIdx.x >> 1;
  const int tid  = threadIdx.x;
  const int lane = tid & 63;
  const int wv   = tid >> 6;

  __shared__ unsigned short Wl[32*512];   // 32 KB, XOR-swizzled
  __shared__ float gs[64*33];             // gate scratch

  for (int i = tid; i < 32*256; i += 256) {
    int e = i*2;
    int row = e >> 9;
    int k   = e & 511;
    int gate = row >> 3, hc = row & 7;
    int grow = gate*H_ + wg*8 + hc;
    const float* wsrc = w_hh + ((size_t)dir*G4 + grow)*H_ + k;
    unsigned int pk = (unsigned int)f2h(wsrc[0]) | ((unsigned int)f2h(wsrc[1]) << 16);
    int byte = row*1024 + ((((k*2) >> 4) ^ (row & 7)) << 4) + ((k*2) & 15);
    *(unsigned int*)((char*)Wl + byte) = pk;
  }
  __syncthreads();

  // preload W fragments into registers
  f16x8 b0r[16], b1r[16];
  {
    const int r0 = lane & 15, r1 = 16 + (lane & 15);
    #pragma unroll
    for (int kt = 0; kt < 16; ++kt) {
      int slot = kt*4 + (lane >> 4);
      b0r[kt] = *(const f16x8*)((const char*)Wl + r0*1024 + ((slot ^ (r0 & 7)) << 4));
      b1r[kt] = *(const f16x8*)((const char*)Wl + r1*1024 + ((slot ^ (r1 & 7)) << 4));
    }
  }

  const int myseq = tid >> 2;
  const int hcA   = (tid & 3)*2;
  const int mylen = lens[myseq];
  const int maxlen = lens[0];
  const int col0  = wg*8;
  const int arow  = wv*16 + (lane & 15);
  float c0 = 0.f, c1 = 0.f, h0k = 0.f, h1k = 0.f;
  unsigned int hold = 0u;

  unsigned short* hbuf0 = &g_hbuf[LAYER][dir][0][0];
  unsigned short* hbuf1 = &g_hbuf[LAYER][dir][1][0];
  unsigned int*   flags = &g_flag[LAYER][dir][0][0];

  const unsigned int h_voff  = (unsigned int)(arow*1024 + ((lane >> 4)*16));
  const unsigned int st_voff = (unsigned int)((myseq*H_ + col0 + hcA)*2);
  const unsigned int fl_voff = (unsigned int)(lane*128);

  const char* xbase = (const char*)((const unsigned int*)
      (g_xproj + (((size_t)dir*B_ + myseq)*T_)*G4 + col0) + (hcA >> 1));

  // prologue: prefetch xg for s=0
  unsigned int r0w, r1w, r2w, r3w;
  {
    int p0 = dir ? (mylen - 1) : 0;
    const char* xr = xbase + (size_t)p0*4096;
    asm volatile("global_load_dword %0, %1, off"             : "=v"(r0w) : "v"(xr) : "memory");
    asm volatile("global_load_dword %0, %1, off offset:1024" : "=v"(r1w) : "v"(xr) : "memory");
    asm volatile("global_load_dword %0, %1, off offset:2048" : "=v"(r2w) : "v"(xr) : "memory");
    asm volatile("global_load_dword %0, %1, off offset:3072" : "=v"(r3w) : "v"(xr) : "memory");
    asm volatile("s_waitcnt vmcnt(0)" ::: "memory");
    __builtin_amdgcn_sched_barrier(0);
  }

  for (int s = 0; s < maxlen; ++s) {
    const unsigned short* hread = (s & 1) ? hbuf1 : hbuf0;
    unsigned short* hwrite      = (s & 1) ? hbuf0 : hbuf1;
    const bool act = s < mylen;

    // ---- 1. batched agent-scope h-load: 16 x dwordx4 sc1, SGPR base + imm offsets ----
    f16x8 aa[16];
#define HLD(I, OFS) asm volatile("global_load_dwordx4 %0, %1, %2 offset:" OFS " sc1" \
                                 : "=v"(aa[I]) : "v"(h_voff), "s"(hread) : "memory")
    HLD(0,"0");   HLD(1,"64");  HLD(2,"128"); HLD(3,"192");
    HLD(4,"256"); HLD(5,"320"); HLD(6,"384"); HLD(7,"448");
    HLD(8,"512"); HLD(9,"576"); HLD(10,"640"); HLD(11,"704");
    HLD(12,"768"); HLD(13,"832"); HLD(14,"896"); HLD(15,"960");
#undef HLD

    // ---- 2. prefetch xg(s+1) (plain cached loads; excluded from the MFMA wait) ----
    unsigned int n0w, n1w, n2w, n3w;
    {
      int s1 = s + 1;
      int p1 = dir ? (mylen - 1 - s1) : s1;
      p1 = p1 < 0 ? 0 : (p1 > mylen - 1 ? mylen - 1 : p1);
      const char* xr = xbase + (size_t)p1*4096;
      asm volatile("global_load_dword %0, %1, off"             : "=v"(n0w) : "v"(xr) : "memory");
      asm volatile("global_load_dword %0, %1, off offset:1024" : "=v"(n1w) : "v"(xr) : "memory");
      asm volatile("global_load_dword %0, %1, off offset:2048" : "=v"(n2w) : "v"(xr) : "memory");
      asm volatile("global_load_dword %0, %1, off offset:3072" : "=v"(n3w) : "v"(xr) : "memory");
    }
    asm volatile("s_waitcnt vmcnt(4)" ::: "memory");   // h-loads done; 4 prefetches fly
    __builtin_amdgcn_sched_barrier(0);

    // ---- 3. recurrent MFMA, two half-depth chains per output ----
    f32x4 a0e = {0.f,0.f,0.f,0.f}, a0o = {0.f,0.f,0.f,0.f};
    f32x4 a1e = {0.f,0.f,0.f,0.f}, a1o = {0.f,0.f,0.f,0.f};
    #pragma unroll
    for (int kt = 0; kt < 16; kt += 2) {
      a0e = __builtin_amdgcn_mfma_f32_16x16x32_f16(aa[kt],   b0r[kt],   a0e, 0, 0, 0);
      a1e = __builtin_amdgcn_mfma_f32_16x16x32_f16(aa[kt],   b1r[kt],   a1e, 0, 0, 0);
      a0o = __builtin_amdgcn_mfma_f32_16x16x32_f16(aa[kt+1], b0r[kt+1], a0o, 0, 0, 0);
      a1o = __builtin_amdgcn_mfma_f32_16x16x32_f16(aa[kt+1], b1r[kt+1], a1o, 0, 0, 0);
    }
    f32x4 acc0 = a0e + a0o;
    f32x4 acc1 = a1e + a1o;

    // ---- 4. same-wave LDS transpose ----
    #pragma unroll
    for (int j = 0; j < 4; ++j) {
      int srow = wv*16 + (lane >> 4)*4 + j;
      gs[srow*33 + (lane & 15)]      = acc0[j];
      gs[srow*33 + 16 + (lane & 15)] = acc1[j];
    }

    // ---- 5. gates (xg from prefetched regs) ----
    {
      f16x2 p0 = __builtin_bit_cast(f16x2, r0w);
      f16x2 p1 = __builtin_bit_cast(f16x2, r1w);
      f16x2 p2 = __builtin_bit_cast(f16x2, r2w);
      f16x2 p3 = __builtin_bit_cast(f16x2, r3w);
      const int q = myseq*33;
      float vi0 = gs[q + hcA]         + (float)p0[0];
      float vi1 = gs[q + hcA + 1]     + (float)p0[1];
      float vf0 = gs[q + 8 + hcA]     + (float)p1[0];
      float vf1 = gs[q + 8 + hcA + 1] + (float)p1[1];
      float vg0 = gs[q + 16 + hcA]    + (float)p2[0];
      float vg1 = gs[q + 16 + hcA+1]  + (float)p2[1];
      float vo0 = gs[q + 24 + hcA]    + (float)p3[0];
      float vo1 = gs[q + 24 + hcA+1]  + (float)p3[1];
      if (act) {
        float i0 = sigf(vi0), f0 = sigf(vf0), G0 = tanh_(vg0), o0 = sigf(vo0);
        float i1 = sigf(vi1), f1 = sigf(vf1), G1 = tanh_(vg1), o1 = sigf(vo1);
        c0 = f0*c0 + i0*G0;
        c1 = f1*c1 + i1*G1;
        h0k = o0*tanh_(c0);
        h1k = o1*tanh_(c1);
        hold = (unsigned int)f2h(h0k) | ((unsigned int)f2h(h1k) << 16);
      }
    }
    r0w = n0w; r1w = n1w; r2w = n2w; r3w = n3w;

    // ---- 6. stores (idempotent; clamped pos) ----
    {
      int pos = dir ? (mylen - 1 - s) : s;
      pos = pos < 0 ? 0 : (pos > mylen - 1 ? mylen - 1 : pos);
      if (LAYER == 0) {
        *(unsigned int*)(g_out1 + ((size_t)myseq*T_ + pos)*1024 + dir*H_ + col0 + hcA) = hold;
      } else {
        g_hlast[dir][myseq*H_ + col0 + hcA]     = h0k;
        g_hlast[dir][myseq*H_ + col0 + hcA + 1] = h1k;
      }
    }
    asm volatile("global_store_dword %0, %1, %2 sc1"
                 :: "v"(st_voff), "v"(hold), "s"(hwrite) : "memory");

    // ---- 7. drain (stores + prefetch), WG rendezvous ----
    asm volatile("s_waitcnt vmcnt(0)\n\ts_barrier" ::: "memory");

    // ---- 8. signal + poll (flags 128B apart; agent scope) ----
    if (tid == 0) {
      unsigned int fv = (unsigned int)(s + 1);
      unsigned int fo = (unsigned int)(wg*128);
      asm volatile("global_store_dword %0, %1, %2 sc1"
                   :: "v"(fo), "v"(fv), "s"(flags) : "memory");
    }
    if (wv == 0) {
      const unsigned int tgt = (unsigned int)(s + 1);
      while (true) {
        unsigned int v;
        asm volatile("global_load_dword %0, %1, %2 sc1"
                     : "=v"(v) : "v"(fl_voff), "s"(flags) : "memory");
        asm volatile("s_waitcnt vmcnt(0)" ::: "memory");
        if (__all(v >= tgt)) break;
        __builtin_amdgcn_s_sleep(1);
      }
    }
    asm volatile("s_barrier" ::: "memory");
  }
}

// ---------------- final projection ----------------
__global__ void k_final(const float* __restrict__ w_out, const float* __restrict__ b_out,
                        float* __restrict__ out) {
  const int b = blockIdx.x;
  const int tid = threadIdx.x;
  float sum = 0.f;
  for (int k = tid; k < 1024; k += 256) {
    float h = (k < 512) ? g_hlast[0][b*H_ + k] : g_hlast[1][b*H_ + k - 512];
    sum += h * w_out[k];
  }
  __shared__ float red[256];
  red[tid] = sum;
  __syncthreads();
  for (int st = 128; st > 0; st >>= 1) {
    if (tid < st) red[tid] += red[tid + st];
    __syncthreads();
  }
  if (tid == 0) out[b] = 1.f/(1.f + __expf(-(red[0] + b_out[0])));
}

// ---------------- launch ----------------
extern "C" void kernel_launch(void* const* d_in, const int* in_sizes, int n_in,
                              void* d_out, int out_size, void* d_ws, size_t ws_size,
                              hipStream_t stream) {
  (void)in_sizes; (void)n_in; (void)d_ws; (void)ws_size; (void)out_size;
  const float* seqs    = (const float*)d_in[0];
  const int*   lens    = (const int*)d_in[1];
  const float* w_ih_l0 = (const float*)d_in[2];
  const float* w_hh_l0 = (const float*)d_in[3];
  const float* b_ih_l0 = (const float*)d_in[4];
  const float* b_hh_l0 = (const float*)d_in[5];
  const float* w_ih_l1 = (const float*)d_in[6];
  const float* w_hh_l1 = (const float*)d_in[7];
  const float* b_ih_l1 = (const float*)d_in[8];
  const float* b_hh_l1 = (const float*)d_in[9];
  const float* w_out   = (const float*)d_in[10];
  const float* b_out   = (const float*)d_in[11];
  float* outp = (float*)d_out;

  hipLaunchKernelGGL(k_init,   dim3(256),  dim3(256), 0, stream);
  hipLaunchKernelGGL(k_cvt_x,  dim3(2048), dim3(256), 0, stream, seqs);
  hipLaunchKernelGGL(k_cvt_w1, dim3(256),  dim3(256), 0, stream, w_ih_l0);
  hipLaunchKernelGGL(k_cvt_w2, dim3(512),  dim3(256), 0, stream, w_ih_l1);

  hipLaunchKernelGGL((k_xproj<0>), dim3(BT_/128, 16, 2), dim3(256), 0, stream,
                     b_ih_l0, b_hh_l0, lens);
  {
    void* args[] = { (void*)&w_hh_l0, (void*)&lens };
    hipError_t e = hipLaunchCooperativeKernel(k_scan<0>, dim3(128), dim3(256), args, 0u, stream);
    (void)e;
  }
  hipLaunchKernelGGL((k_xproj<1>), dim3(BT_/128, 16, 2), dim3(256), 0, stream,
                     b_ih_l1, b_hh_l1, lens);
  {
    void* args[] = { (void*)&w_hh_l1, (void*)&lens };
    hipError_t e = hipLaunchCooperativeKernel(k_scan<1>, dim3(128), dim3(256), args, 0u, stream);
    (void)e;
  }
  hipLaunchKernelGGL(k_final, dim3(64), dim3(256), 0, stream, w_out, b_out, outp);
}

// Round 9
// 18897.801 us; speedup vs baseline: 3.0545x; 1.0137x over previous
//
#include <hip/hip_runtime.h>
#include <stdint.h>
#include <stddef.h>

#define B_  64
#define T_  2048
#define XD  256
#define H_  512
#define G4  2048          // 4*H
#define BT_ (B_*T_)       // 131072

typedef __attribute__((ext_vector_type(8))) _Float16 f16x8;
typedef __attribute__((ext_vector_type(4))) float f32x4;
typedef __attribute__((ext_vector_type(4))) unsigned int u32x4;
typedef __attribute__((ext_vector_type(4))) unsigned short us4;
typedef __attribute__((ext_vector_type(2))) _Float16 f16x2;

// ---------------- static device scratch (total ~1.42 GB < 2 GiB PC32-reloc budget) ----
__device__ __attribute__((aligned(256))) unsigned short g_xh[(size_t)BT_*XD];         // x fp16
__device__ __attribute__((aligned(256))) unsigned short g_w1h[(size_t)2*G4*XD];       // w_ih_l0 fp16
__device__ __attribute__((aligned(256))) unsigned short g_w2h[(size_t)2*G4*1024];     // w_ih_l1 fp16
__device__ __attribute__((aligned(256))) _Float16       g_xproj[(size_t)2*BT_*G4];    // 1.07 GB fp16
__device__ __attribute__((aligned(256))) unsigned short g_out1[(size_t)BT_*1024];     // 268 MB fp16
__device__ __attribute__((aligned(256))) unsigned short g_hbuf[2][2][2][B_*H_];       // [layer][dir][pp] fp16
__device__ __attribute__((aligned(256))) float          g_hlast[2][B_*H_];            // layer2 final h
__device__ __attribute__((aligned(256))) unsigned int   g_flag[2][2][64][32];         // [layer][dir][wg][pad128B]

__device__ inline unsigned short f2h(float f) {
  _Float16 h = (_Float16)f;
  return __builtin_bit_cast(unsigned short, h);
}
__device__ inline float sigf(float x)  { return 1.f/(1.f + __expf(-x)); }
__device__ inline float tanh_(float x) { return 1.f - 2.f/(__expf(2.f*x) + 1.f); }

// ---------------- init: zero h buffers + flags (every call) ----------------
__global__ void k_init() {
  unsigned int i = blockIdx.x*256u + threadIdx.x;
  unsigned int stride = gridDim.x*256u;
  unsigned int* hb = (unsigned int*)&g_hbuf[0][0][0][0];
  for (unsigned int j = i; j < sizeof(g_hbuf)/4; j += stride) hb[j] = 0u;
  unsigned int* fl = (unsigned int*)&g_flag[0][0][0][0];
  for (unsigned int j = i; j < sizeof(g_flag)/4; j += stride) fl[j] = 0u;
}

// ---------------- fp32 -> fp16 converts ----------------
__global__ void k_cvt_x(const float* __restrict__ src) {
  const size_t n4 = (size_t)BT_*XD/4;
  for (size_t j = (size_t)blockIdx.x*blockDim.x + threadIdx.x; j < n4;
       j += (size_t)gridDim.x*blockDim.x) {
    float4 v = ((const float4*)src)[j];
    us4 o = { f2h(v.x), f2h(v.y), f2h(v.z), f2h(v.w) };
    ((us4*)g_xh)[j] = o;
  }
}
__global__ void k_cvt_w1(const float* __restrict__ src) {
  const size_t n4 = (size_t)2*G4*XD/4;
  for (size_t j = (size_t)blockIdx.x*blockDim.x + threadIdx.x; j < n4;
       j += (size_t)gridDim.x*blockDim.x) {
    float4 v = ((const float4*)src)[j];
    us4 o = { f2h(v.x), f2h(v.y), f2h(v.z), f2h(v.w) };
    ((us4*)g_w1h)[j] = o;
  }
}
__global__ void k_cvt_w2(const float* __restrict__ src) {
  const size_t n4 = (size_t)2*G4*1024/4;
  for (size_t j = (size_t)blockIdx.x*blockDim.x + threadIdx.x; j < n4;
       j += (size_t)gridDim.x*blockDim.x) {
    float4 v = ((const float4*)src)[j];
    us4 o = { f2h(v.x), f2h(v.y), f2h(v.z), f2h(v.w) };
    ((us4*)g_w2h)[j] = o;
  }
}

// ---------------- x_proj GEMM (unchanged) ----------------
template<int LAYER>
__global__ __launch_bounds__(256) void k_xproj(const float* __restrict__ b_ih,
                                               const float* __restrict__ b_hh,
                                               const int* __restrict__ lens) {
  constexpr int K = (LAYER == 0) ? XD : 1024;
  const unsigned short* __restrict__ Abf = (LAYER == 0) ? g_xh : g_out1;
  const unsigned short* __restrict__ Wbf = (LAYER == 0) ? g_w1h : g_w2h;

  const int m0 = blockIdx.x*128;
  const int n0 = blockIdx.y*128;
  const int d  = blockIdx.z;
  const int bseq = m0 / T_;
  const int t0   = m0 % T_;
  if (t0 >= lens[bseq]) return;

  __shared__ unsigned short As[128*64];
  __shared__ unsigned short Bs[128*64];

  const int tid  = threadIdx.x;
  const int lane = tid & 63;
  const int wv   = tid >> 6;
  const int moff = (wv >> 1)*64;
  const int noff = (wv & 1)*64;

  f32x4 acc[4][4] = {};

  const unsigned short* Ag = Abf + (size_t)m0*K;
  const unsigned short* Wg = Wbf + ((size_t)d*G4 + n0)*K;

  for (int k0 = 0; k0 < K; k0 += 64) {
    __syncthreads();
    #pragma unroll
    for (int p = 0; p < 4; ++p) {
      int sidx = p*256 + tid;
      int row = sidx >> 3;
      int ch  = sidx & 7;
      u32x4 va = *(const u32x4*)(Ag + (size_t)row*K + k0 + ch*8);
      u32x4 vb = *(const u32x4*)(Wg + (size_t)row*K + k0 + ch*8);
      int wb = row*128 + ((ch ^ (row & 7)) << 4);
      *(u32x4*)((char*)As + wb) = va;
      *(u32x4*)((char*)Bs + wb) = vb;
    }
    __syncthreads();
    #pragma unroll
    for (int kt = 0; kt < 2; ++kt) {
      int slot = kt*4 + (lane >> 4);
      f16x8 af[4], bfv[4];
      #pragma unroll
      for (int mt = 0; mt < 4; ++mt) {
        int r = moff + mt*16 + (lane & 15);
        af[mt] = *(const f16x8*)((const char*)As + r*128 + ((slot ^ (r & 7)) << 4));
      }
      #pragma unroll
      for (int nt = 0; nt < 4; ++nt) {
        int r = noff + nt*16 + (lane & 15);
        bfv[nt] = *(const f16x8*)((const char*)Bs + r*128 + ((slot ^ (r & 7)) << 4));
      }
      #pragma unroll
      for (int mt = 0; mt < 4; ++mt)
        #pragma unroll
        for (int nt = 0; nt < 4; ++nt)
          acc[mt][nt] = __builtin_amdgcn_mfma_f32_16x16x32_f16(af[mt], bfv[nt], acc[mt][nt], 0, 0, 0);
    }
  }

  #pragma unroll
  for (int nt = 0; nt < 4; ++nt) {
    const int col = n0 + noff + nt*16 + (lane & 15);
    const float bias = b_ih[d*G4 + col] + b_hh[d*G4 + col];
    #pragma unroll
    for (int mt = 0; mt < 4; ++mt) {
      const int row = m0 + moff + mt*16 + (lane >> 4)*4;
      _Float16* op = g_xproj + ((size_t)d*BT_ + row)*G4 + col;
      #pragma unroll
      for (int j = 0; j < 4; ++j)
        op[(size_t)j*G4] = (_Float16)(acc[mt][nt][j] + bias);
    }
  }
}

// ---------------- recurrent scan ----------------
// 128 blocks: dir=bid&1, wg=bid>>1. WG owns h-cols [wg*8,wg*8+8).
// Schedule per step:
//   1. issue 16 h-loads (sc1, LLC)            [vm]
//   2. issue 32 W-frag ds_reads (in h shadow) [lgkm]
//   3. vmcnt(0) + sched_barrier -> consume prefetched xg into cur regs
//   4. MFMA (lgkm auto-waited) ; gs transpose ; gates
//   5. stores: out1/hlast (plain) + h (sc1)
//   6. issue xg(s+1) prefetch (plain, HBM)
//   7. vmcnt(4): stores acked, prefetch FLIES ACROSS THE BARRIER (T4)
//   8. s_barrier ; tid0 flag (sc1, 128B-spaced) ; wave0 poll ; s_barrier
template<int LAYER>
__global__ __launch_bounds__(256, 1) void k_scan(const float* __restrict__ w_hh,
                                                 const int* __restrict__ lens) {
  const int dir  = blockIdx.x & 1;
  const int wg   = blockIdx.x >> 1;
  const int tid  = threadIdx.x;
  const int lane = tid & 63;
  const int wv   = tid >> 6;

  __shared__ unsigned short Wl[32*512];   // 32 KB, XOR-swizzled
  __shared__ float gs[64*33];             // gate scratch

  for (int i = tid; i < 32*256; i += 256) {
    int e = i*2;
    int row = e >> 9;
    int k   = e & 511;
    int gate = row >> 3, hc = row & 7;
    int grow = gate*H_ + wg*8 + hc;
    const float* wsrc = w_hh + ((size_t)dir*G4 + grow)*H_ + k;
    unsigned int pk = (unsigned int)f2h(wsrc[0]) | ((unsigned int)f2h(wsrc[1]) << 16);
    int byte = row*1024 + ((((k*2) >> 4) ^ (row & 7)) << 4) + ((k*2) & 15);
    *(unsigned int*)((char*)Wl + byte) = pk;
  }
  __syncthreads();

  const int myseq = tid >> 2;
  const int hcA   = (tid & 3)*2;
  const int mylen = lens[myseq];
  const int maxlen = lens[0];
  const int col0  = wg*8;
  const int arow  = wv*16 + (lane & 15);
  const int r0f   = lane & 15, r1f = 16 + (lane & 15);
  float c0 = 0.f, c1 = 0.f, h0k = 0.f, h1k = 0.f;
  unsigned int hold = 0u;

  unsigned short* hbuf0 = &g_hbuf[LAYER][dir][0][0];
  unsigned short* hbuf1 = &g_hbuf[LAYER][dir][1][0];
  unsigned int*   flags = &g_flag[LAYER][dir][0][0];

  const unsigned int h_voff  = (unsigned int)(arow*1024 + ((lane >> 4)*16));
  const unsigned int st_voff = (unsigned int)((myseq*H_ + col0 + hcA)*2);
  const unsigned int fl_voff = (unsigned int)(lane*128);

  const char* xbase = (const char*)((const unsigned int*)
      (g_xproj + (((size_t)dir*B_ + myseq)*T_)*G4 + col0) + (hcA >> 1));

  // prologue: prefetch xg for s=0 into nx*
  unsigned int nx0, nx1, nx2, nx3;
  {
    int p0 = dir ? (mylen - 1) : 0;
    const char* xr = xbase + (size_t)p0*4096;
    asm volatile("global_load_dword %0, %1, off"             : "=v"(nx0) : "v"(xr) : "memory");
    asm volatile("global_load_dword %0, %1, off offset:1024" : "=v"(nx1) : "v"(xr) : "memory");
    asm volatile("global_load_dword %0, %1, off offset:2048" : "=v"(nx2) : "v"(xr) : "memory");
    asm volatile("global_load_dword %0, %1, off offset:3072" : "=v"(nx3) : "v"(xr) : "memory");
  }

  for (int s = 0; s < maxlen; ++s) {
    const unsigned short* hread = (s & 1) ? hbuf1 : hbuf0;
    unsigned short* hwrite      = (s & 1) ? hbuf0 : hbuf1;
    const bool act = s < mylen;

    // ---- 1. batched agent-scope h-load: 16 x dwordx4 sc1 ----
    f16x8 aa[16];
#define HLD(I, OFS) asm volatile("global_load_dwordx4 %0, %1, %2 offset:" OFS " sc1" \
                                 : "=v"(aa[I]) : "v"(h_voff), "s"(hread) : "memory")
    HLD(0,"0");   HLD(1,"64");  HLD(2,"128"); HLD(3,"192");
    HLD(4,"256"); HLD(5,"320"); HLD(6,"384"); HLD(7,"448");
    HLD(8,"512"); HLD(9,"576"); HLD(10,"640"); HLD(11,"704");
    HLD(12,"768"); HLD(13,"832"); HLD(14,"896"); HLD(15,"960");
#undef HLD

    // ---- 2. W-fragment ds_reads in the h-load shadow (lgkm counter) ----
    f16x8 b0r[16], b1r[16];
    #pragma unroll
    for (int kt = 0; kt < 16; ++kt) {
      int slot = kt*4 + (lane >> 4);
      b0r[kt] = *(const f16x8*)((const char*)Wl + r0f*1024 + ((slot ^ (r0f & 7)) << 4));
      b1r[kt] = *(const f16x8*)((const char*)Wl + r1f*1024 + ((slot ^ (r1f & 7)) << 4));
    }

    // ---- 3. h (and prior xg) complete; then consume xg safely ----
    asm volatile("s_waitcnt vmcnt(0)" ::: "memory");
    __builtin_amdgcn_sched_barrier(0);
    unsigned int x0 = nx0, x1 = nx1, x2 = nx2, x3 = nx3;

    // ---- 4. recurrent MFMA, two half-depth chains per output ----
    f32x4 a0e = {0.f,0.f,0.f,0.f}, a0o = {0.f,0.f,0.f,0.f};
    f32x4 a1e = {0.f,0.f,0.f,0.f}, a1o = {0.f,0.f,0.f,0.f};
    #pragma unroll
    for (int kt = 0; kt < 16; kt += 2) {
      a0e = __builtin_amdgcn_mfma_f32_16x16x32_f16(aa[kt],   b0r[kt],   a0e, 0, 0, 0);
      a1e = __builtin_amdgcn_mfma_f32_16x16x32_f16(aa[kt],   b1r[kt],   a1e, 0, 0, 0);
      a0o = __builtin_amdgcn_mfma_f32_16x16x32_f16(aa[kt+1], b0r[kt+1], a0o, 0, 0, 0);
      a1o = __builtin_amdgcn_mfma_f32_16x16x32_f16(aa[kt+1], b1r[kt+1], a1o, 0, 0, 0);
    }
    f32x4 acc0 = a0e + a0o;
    f32x4 acc1 = a1e + a1o;

    // ---- gs transpose (same-wave produce/consume) ----
    #pragma unroll
    for (int j = 0; j < 4; ++j) {
      int srow = wv*16 + (lane >> 4)*4 + j;
      gs[srow*33 + (lane & 15)]      = acc0[j];
      gs[srow*33 + 16 + (lane & 15)] = acc1[j];
    }

    // ---- gates (xg from x0..x3) ----
    {
      f16x2 p0 = __builtin_bit_cast(f16x2, x0);
      f16x2 p1 = __builtin_bit_cast(f16x2, x1);
      f16x2 p2 = __builtin_bit_cast(f16x2, x2);
      f16x2 p3 = __builtin_bit_cast(f16x2, x3);
      const int q = myseq*33;
      float vi0 = gs[q + hcA]         + (float)p0[0];
      float vi1 = gs[q + hcA + 1]     + (float)p0[1];
      float vf0 = gs[q + 8 + hcA]     + (float)p1[0];
      float vf1 = gs[q + 8 + hcA + 1] + (float)p1[1];
      float vg0 = gs[q + 16 + hcA]    + (float)p2[0];
      float vg1 = gs[q + 16 + hcA+1]  + (float)p2[1];
      float vo0 = gs[q + 24 + hcA]    + (float)p3[0];
      float vo1 = gs[q + 24 + hcA+1]  + (float)p3[1];
      if (act) {
        float i0 = sigf(vi0), f0 = sigf(vf0), G0 = tanh_(vg0), o0 = sigf(vo0);
        float i1 = sigf(vi1), f1 = sigf(vf1), G1 = tanh_(vg1), o1 = sigf(vo1);
        c0 = f0*c0 + i0*G0;
        c1 = f1*c1 + i1*G1;
        h0k = o0*tanh_(c0);
        h1k = o1*tanh_(c1);
        hold = (unsigned int)f2h(h0k) | ((unsigned int)f2h(h1k) << 16);
      }
    }

    // ---- 5. stores (idempotent; clamped pos) ----
    {
      int pos = dir ? (mylen - 1 - s) : s;
      pos = pos < 0 ? 0 : (pos > mylen - 1 ? mylen - 1 : pos);
      if (LAYER == 0) {
        *(unsigned int*)(g_out1 + ((size_t)myseq*T_ + pos)*1024 + dir*H_ + col0 + hcA) = hold;
      } else {
        g_hlast[dir][myseq*H_ + col0 + hcA]     = h0k;
        g_hlast[dir][myseq*H_ + col0 + hcA + 1] = h1k;
      }
    }
    asm volatile("global_store_dword %0, %1, %2 sc1"
                 :: "v"(st_voff), "v"(hold), "s"(hwrite) : "memory");

    // ---- 6. issue xg(s+1) prefetch AFTER stores (rides across the barrier) ----
    {
      int s1 = s + 1;
      int p1 = dir ? (mylen - 1 - s1) : s1;
      p1 = p1 < 0 ? 0 : (p1 > mylen - 1 ? mylen - 1 : p1);
      const char* xr = xbase + (size_t)p1*4096;
      asm volatile("global_load_dword %0, %1, off"             : "=v"(nx0) : "v"(xr) : "memory");
      asm volatile("global_load_dword %0, %1, off offset:1024" : "=v"(nx1) : "v"(xr) : "memory");
      asm volatile("global_load_dword %0, %1, off offset:2048" : "=v"(nx2) : "v"(xr) : "memory");
      asm volatile("global_load_dword %0, %1, off offset:3072" : "=v"(nx3) : "v"(xr) : "memory");
    }

    // ---- 7. drain stores only (4 prefetch loads keep flying) ----
    asm volatile("s_waitcnt vmcnt(4)\n\ts_barrier" ::: "memory");

    // ---- 8. signal + poll ----
    if (tid == 0) {
      unsigned int fv = (unsigned int)(s + 1);
      unsigned int fo = (unsigned int)(wg*128);
      asm volatile("global_store_dword %0, %1, %2 sc1"
                   :: "v"(fo), "v"(fv), "s"(flags) : "memory");
    }
    if (wv == 0) {
      const unsigned int tgt = (unsigned int)(s + 1);
      while (true) {
        unsigned int v;
        asm volatile("global_load_dword %0, %1, %2 sc1"
                     : "=v"(v) : "v"(fl_voff), "s"(flags) : "memory");
        asm volatile("s_waitcnt vmcnt(0)" ::: "memory");
        if (__all(v >= tgt)) break;
        __builtin_amdgcn_s_sleep(1);
      }
    }
    asm volatile("s_barrier" ::: "memory");
  }
}

// ---------------- final projection ----------------
__global__ void k_final(const float* __restrict__ w_out, const float* __restrict__ b_out,
                        float* __restrict__ out) {
  const int b = blockIdx.x;
  const int tid = threadIdx.x;
  float sum = 0.f;
  for (int k = tid; k < 1024; k += 256) {
    float h = (k < 512) ? g_hlast[0][b*H_ + k] : g_hlast[1][b*H_ + k - 512];
    sum += h * w_out[k];
  }
  __shared__ float red[256];
  red[tid] = sum;
  __syncthreads();
  for (int st = 128; st > 0; st >>= 1) {
    if (tid < st) red[tid] += red[tid + st];
    __syncthreads();
  }
  if (tid == 0) out[b] = 1.f/(1.f + __expf(-(red[0] + b_out[0])));
}

// ---------------- launch ----------------
extern "C" void kernel_launch(void* const* d_in, const int* in_sizes, int n_in,
                              void* d_out, int out_size, void* d_ws, size_t ws_size,
                              hipStream_t stream) {
  (void)in_sizes; (void)n_in; (void)d_ws; (void)ws_size; (void)out_size;
  const float* seqs    = (const float*)d_in[0];
  const int*   lens    = (const int*)d_in[1];
  const float* w_ih_l0 = (const float*)d_in[2];
  const float* w_hh_l0 = (const float*)d_in[3];
  const float* b_ih_l0 = (const float*)d_in[4];
  const float* b_hh_l0 = (const float*)d_in[5];
  const float* w_ih_l1 = (const float*)d_in[6];
  const float* w_hh_l1 = (const float*)d_in[7];
  const float* b_ih_l1 = (const float*)d_in[8];
  const float* b_hh_l1 = (const float*)d_in[9];
  const float* w_out   = (const float*)d_in[10];
  const float* b_out   = (const float*)d_in[11];
  float* outp = (float*)d_out;

  hipLaunchKernelGGL(k_init,   dim3(256),  dim3(256), 0, stream);
  hipLaunchKernelGGL(k_cvt_x,  dim3(2048), dim3(256), 0, stream, seqs);
  hipLaunchKernelGGL(k_cvt_w1, dim3(256),  dim3(256), 0, stream, w_ih_l0);
  hipLaunchKernelGGL(k_cvt_w2, dim3(512),  dim3(256), 0, stream, w_ih_l1);

  hipLaunchKernelGGL((k_xproj<0>), dim3(BT_/128, 16, 2), dim3(256), 0, stream,
                     b_ih_l0, b_hh_l0, lens);
  {
    void* args[] = { (void*)&w_hh_l0, (void*)&lens };
    hipError_t e = hipLaunchCooperativeKernel(k_scan<0>, dim3(128), dim3(256), args, 0u, stream);
    (void)e;
  }
  hipLaunchKernelGGL((k_xproj<1>), dim3(BT_/128, 16, 2), dim3(256), 0, stream,
                     b_ih_l1, b_hh_l1, lens);
  {
    void* args[] = { (void*)&w_hh_l1, (void*)&lens };
    hipError_t e = hipLaunchCooperativeKernel(k_scan<1>, dim3(128), dim3(256), args, 0u, stream);
    (void)e;
  }
  hipLaunchKernelGGL(k_final, dim3(64), dim3(256), 0, stream, w_out, b_out, outp);
}

// Round 10
// 17109.901 us; speedup vs baseline: 3.3737x; 1.1045x over previous
//
#include <hip/hip_runtime.h>
#include <stdint.h>
#include <stddef.h>

#define B_  64
#define T_  2048
#define XD  256
#define H_  512
#define G4  2048          // 4*H
#define BT_ (B_*T_)       // 131072

typedef __attribute__((ext_vector_type(8))) _Float16 f16x8;
typedef __attribute__((ext_vector_type(4))) float f32x4;
typedef __attribute__((ext_vector_type(4))) unsigned int u32x4;
typedef __attribute__((ext_vector_type(4))) unsigned short us4;
typedef __attribute__((ext_vector_type(2))) _Float16 f16x2;

// ---------------- static device scratch (total ~1.42 GB < 2 GiB PC32-reloc budget) ----
__device__ __attribute__((aligned(256))) unsigned short g_xh[(size_t)BT_*XD];         // x fp16
__device__ __attribute__((aligned(256))) unsigned short g_w1h[(size_t)2*G4*XD];       // w_ih_l0 fp16
__device__ __attribute__((aligned(256))) unsigned short g_w2h[(size_t)2*G4*1024];     // w_ih_l1 fp16
__device__ __attribute__((aligned(256))) _Float16       g_xproj[(size_t)2*BT_*G4];    // 1.07 GB fp16
__device__ __attribute__((aligned(256))) unsigned short g_out1[(size_t)BT_*1024];     // 268 MB fp16
__device__ __attribute__((aligned(256))) unsigned short g_hbuf[2][2][2][B_*H_];       // [layer][dir][pp] fp16
__device__ __attribute__((aligned(256))) float          g_hlast[2][B_*H_];            // layer2 final h
// fanout flags: [layer][dir][reader wg][writer wg] -> reader's 64 dwords contiguous (256B)
__device__ __attribute__((aligned(256))) unsigned int   g_flag[2][2][64][64];

__device__ inline unsigned short f2h(float f) {
  _Float16 h = (_Float16)f;
  return __builtin_bit_cast(unsigned short, h);
}
__device__ inline float sigf(float x)  { return 1.f/(1.f + __expf(-x)); }
__device__ inline float tanh_(float x) { return 1.f - 2.f/(__expf(2.f*x) + 1.f); }

// ---------------- init: zero h buffers + flags (every call) ----------------
__global__ void k_init() {
  unsigned int i = blockIdx.x*256u + threadIdx.x;
  unsigned int stride = gridDim.x*256u;
  unsigned int* hb = (unsigned int*)&g_hbuf[0][0][0][0];
  for (unsigned int j = i; j < sizeof(g_hbuf)/4; j += stride) hb[j] = 0u;
  unsigned int* fl = (unsigned int*)&g_flag[0][0][0][0];
  for (unsigned int j = i; j < sizeof(g_flag)/4; j += stride) fl[j] = 0u;
}

// ---------------- fp32 -> fp16 converts ----------------
__global__ void k_cvt_x(const float* __restrict__ src) {
  const size_t n4 = (size_t)BT_*XD/4;
  for (size_t j = (size_t)blockIdx.x*blockDim.x + threadIdx.x; j < n4;
       j += (size_t)gridDim.x*blockDim.x) {
    float4 v = ((const float4*)src)[j];
    us4 o = { f2h(v.x), f2h(v.y), f2h(v.z), f2h(v.w) };
    ((us4*)g_xh)[j] = o;
  }
}
__global__ void k_cvt_w1(const float* __restrict__ src) {
  const size_t n4 = (size_t)2*G4*XD/4;
  for (size_t j = (size_t)blockIdx.x*blockDim.x + threadIdx.x; j < n4;
       j += (size_t)gridDim.x*blockDim.x) {
    float4 v = ((const float4*)src)[j];
    us4 o = { f2h(v.x), f2h(v.y), f2h(v.z), f2h(v.w) };
    ((us4*)g_w1h)[j] = o;
  }
}
__global__ void k_cvt_w2(const float* __restrict__ src) {
  const size_t n4 = (size_t)2*G4*1024/4;
  for (size_t j = (size_t)blockIdx.x*blockDim.x + threadIdx.x; j < n4;
       j += (size_t)gridDim.x*blockDim.x) {
    float4 v = ((const float4*)src)[j];
    us4 o = { f2h(v.x), f2h(v.y), f2h(v.z), f2h(v.w) };
    ((us4*)g_w2h)[j] = o;
  }
}

// ---------------- x_proj GEMM (unchanged) ----------------
template<int LAYER>
__global__ __launch_bounds__(256) void k_xproj(const float* __restrict__ b_ih,
                                               const float* __restrict__ b_hh,
                                               const int* __restrict__ lens) {
  constexpr int K = (LAYER == 0) ? XD : 1024;
  const unsigned short* __restrict__ Abf = (LAYER == 0) ? g_xh : g_out1;
  const unsigned short* __restrict__ Wbf = (LAYER == 0) ? g_w1h : g_w2h;

  const int m0 = blockIdx.x*128;
  const int n0 = blockIdx.y*128;
  const int d  = blockIdx.z;
  const int bseq = m0 / T_;
  const int t0   = m0 % T_;
  if (t0 >= lens[bseq]) return;

  __shared__ unsigned short As[128*64];
  __shared__ unsigned short Bs[128*64];

  const int tid  = threadIdx.x;
  const int lane = tid & 63;
  const int wv   = tid >> 6;
  const int moff = (wv >> 1)*64;
  const int noff = (wv & 1)*64;

  f32x4 acc[4][4] = {};

  const unsigned short* Ag = Abf + (size_t)m0*K;
  const unsigned short* Wg = Wbf + ((size_t)d*G4 + n0)*K;

  for (int k0 = 0; k0 < K; k0 += 64) {
    __syncthreads();
    #pragma unroll
    for (int p = 0; p < 4; ++p) {
      int sidx = p*256 + tid;
      int row = sidx >> 3;
      int ch  = sidx & 7;
      u32x4 va = *(const u32x4*)(Ag + (size_t)row*K + k0 + ch*8);
      u32x4 vb = *(const u32x4*)(Wg + (size_t)row*K + k0 + ch*8);
      int wb = row*128 + ((ch ^ (row & 7)) << 4);
      *(u32x4*)((char*)As + wb) = va;
      *(u32x4*)((char*)Bs + wb) = vb;
    }
    __syncthreads();
    #pragma unroll
    for (int kt = 0; kt < 2; ++kt) {
      int slot = kt*4 + (lane >> 4);
      f16x8 af[4], bfv[4];
      #pragma unroll
      for (int mt = 0; mt < 4; ++mt) {
        int r = moff + mt*16 + (lane & 15);
        af[mt] = *(const f16x8*)((const char*)As + r*128 + ((slot ^ (r & 7)) << 4));
      }
      #pragma unroll
      for (int nt = 0; nt < 4; ++nt) {
        int r = noff + nt*16 + (lane & 15);
        bfv[nt] = *(const f16x8*)((const char*)Bs + r*128 + ((slot ^ (r & 7)) << 4));
      }
      #pragma unroll
      for (int mt = 0; mt < 4; ++mt)
        #pragma unroll
        for (int nt = 0; nt < 4; ++nt)
          acc[mt][nt] = __builtin_amdgcn_mfma_f32_16x16x32_f16(af[mt], bfv[nt], acc[mt][nt], 0, 0, 0);
    }
  }

  #pragma unroll
  for (int nt = 0; nt < 4; ++nt) {
    const int col = n0 + noff + nt*16 + (lane & 15);
    const float bias = b_ih[d*G4 + col] + b_hh[d*G4 + col];
    #pragma unroll
    for (int mt = 0; mt < 4; ++mt) {
      const int row = m0 + moff + mt*16 + (lane >> 4)*4;
      _Float16* op = g_xproj + ((size_t)d*BT_ + row)*G4 + col;
      #pragma unroll
      for (int j = 0; j < 4; ++j)
        op[(size_t)j*G4] = (_Float16)(acc[mt][nt][j] + bias);
    }
  }
}

// ---------------- recurrent scan ----------------
// 128 blocks: dir=bid&1, wg=bid>>1. WG owns h-cols [wg*8,wg*8+8).
// Fanout barrier: writer wave0 stores epoch to 64 per-READER slots (1 wave store);
// reader polls its OWN contiguous 256B block (4 lines). Wave-level tail skip:
// wave wv active iff s < lens[16wv] (sorted desc; wave0 never skips -> it polls).
// h-store runs one extra step (s<=mylen) so both ping-pong buffers hold frozen h.
template<int LAYER>
__global__ __launch_bounds__(256, 1) void k_scan(const float* __restrict__ w_hh,
                                                 const int* __restrict__ lens) {
  const int dir  = blockIdx.x & 1;
  const int wg   = blockIdx.x >> 1;
  const int tid  = threadIdx.x;
  const int lane = tid & 63;
  const int wv   = tid >> 6;

  __shared__ unsigned short Wl[32*512];   // 32 KB, XOR-swizzled
  __shared__ float gs[64*33];             // gate scratch

  for (int i = tid; i < 32*256; i += 256) {
    int e = i*2;
    int row = e >> 9;
    int k   = e & 511;
    int gate = row >> 3, hc = row & 7;
    int grow = gate*H_ + wg*8 + hc;
    const float* wsrc = w_hh + ((size_t)dir*G4 + grow)*H_ + k;
    unsigned int pk = (unsigned int)f2h(wsrc[0]) | ((unsigned int)f2h(wsrc[1]) << 16);
    int byte = row*1024 + ((((k*2) >> 4) ^ (row & 7)) << 4) + ((k*2) & 15);
    *(unsigned int*)((char*)Wl + byte) = pk;
  }
  __syncthreads();

  const int myseq = tid >> 2;
  const int hcA   = (tid & 3)*2;
  const int mylen = lens[myseq];
  const int maxlen = lens[0];
  const int ml16  = __builtin_amdgcn_readfirstlane(lens[wv << 4]); // wave max len (SGPR)
  const int col0  = wg*8;
  const int arow  = wv*16 + (lane & 15);
  const int r0f   = lane & 15, r1f = 16 + (lane & 15);
  float c0 = 0.f, c1 = 0.f, h0k = 0.f, h1k = 0.f;
  unsigned int hold = 0u;

  unsigned short* hbuf0 = &g_hbuf[LAYER][dir][0][0];
  unsigned short* hbuf1 = &g_hbuf[LAYER][dir][1][0];
  unsigned int*   flags = &g_flag[LAYER][dir][0][0];

  const unsigned int h_voff   = (unsigned int)(arow*1024 + ((lane >> 4)*16));
  const unsigned int st_voff  = (unsigned int)((myseq*H_ + col0 + hcA)*2);
  const unsigned int fan_voff = (unsigned int)(lane*256 + wg*4);   // writer: per-reader slot
  const unsigned int pol_voff = (unsigned int)(wg*256 + lane*4);   // reader: own block

  const char* xbase = (const char*)((const unsigned int*)
      (g_xproj + (((size_t)dir*B_ + myseq)*T_)*G4 + col0) + (hcA >> 1));

  // prologue: prefetch xg for s=0 into nx*
  unsigned int nx0, nx1, nx2, nx3;
  {
    int p0 = dir ? (mylen - 1) : 0;
    const char* xr = xbase + (size_t)p0*4096;
    asm volatile("global_load_dword %0, %1, off"             : "=v"(nx0) : "v"(xr) : "memory");
    asm volatile("global_load_dword %0, %1, off offset:1024" : "=v"(nx1) : "v"(xr) : "memory");
    asm volatile("global_load_dword %0, %1, off offset:2048" : "=v"(nx2) : "v"(xr) : "memory");
    asm volatile("global_load_dword %0, %1, off offset:3072" : "=v"(nx3) : "v"(xr) : "memory");
  }

  for (int s = 0; s < maxlen; ++s) {
    const unsigned short* hread = (s & 1) ? hbuf1 : hbuf0;
    unsigned short* hwrite      = (s & 1) ? hbuf0 : hbuf1;

    if (s < ml16) {   // scalar branch: whole wave skips when its 16 seqs are done
      const bool act = s < mylen;

      // ---- 1. batched agent-scope h-load: 16 x dwordx4 sc1 ----
      f16x8 aa[16];
#define HLD(I, OFS) asm volatile("global_load_dwordx4 %0, %1, %2 offset:" OFS " sc1" \
                                 : "=v"(aa[I]) : "v"(h_voff), "s"(hread) : "memory")
      HLD(0,"0");   HLD(1,"64");  HLD(2,"128"); HLD(3,"192");
      HLD(4,"256"); HLD(5,"320"); HLD(6,"384"); HLD(7,"448");
      HLD(8,"512"); HLD(9,"576"); HLD(10,"640"); HLD(11,"704");
      HLD(12,"768"); HLD(13,"832"); HLD(14,"896"); HLD(15,"960");
#undef HLD

      // ---- 2. W-fragment ds_reads in the h-load shadow ----
      f16x8 b0r[16], b1r[16];
      #pragma unroll
      for (int kt = 0; kt < 16; ++kt) {
        int slot = kt*4 + (lane >> 4);
        b0r[kt] = *(const f16x8*)((const char*)Wl + r0f*1024 + ((slot ^ (r0f & 7)) << 4));
        b1r[kt] = *(const f16x8*)((const char*)Wl + r1f*1024 + ((slot ^ (r1f & 7)) << 4));
      }

      // ---- 3. h (and prior xg) complete; consume xg safely ----
      asm volatile("s_waitcnt vmcnt(0)" ::: "memory");
      __builtin_amdgcn_sched_barrier(0);
      unsigned int x0 = nx0, x1 = nx1, x2 = nx2, x3 = nx3;

      // ---- 4. recurrent MFMA, two half-depth chains ----
      f32x4 a0e = {0.f,0.f,0.f,0.f}, a0o = {0.f,0.f,0.f,0.f};
      f32x4 a1e = {0.f,0.f,0.f,0.f}, a1o = {0.f,0.f,0.f,0.f};
      #pragma unroll
      for (int kt = 0; kt < 16; kt += 2) {
        a0e = __builtin_amdgcn_mfma_f32_16x16x32_f16(aa[kt],   b0r[kt],   a0e, 0, 0, 0);
        a1e = __builtin_amdgcn_mfma_f32_16x16x32_f16(aa[kt],   b1r[kt],   a1e, 0, 0, 0);
        a0o = __builtin_amdgcn_mfma_f32_16x16x32_f16(aa[kt+1], b0r[kt+1], a0o, 0, 0, 0);
        a1o = __builtin_amdgcn_mfma_f32_16x16x32_f16(aa[kt+1], b1r[kt+1], a1o, 0, 0, 0);
      }
      f32x4 acc0 = a0e + a0o;
      f32x4 acc1 = a1e + a1o;

      // ---- gs transpose (same-wave produce/consume) ----
      #pragma unroll
      for (int j = 0; j < 4; ++j) {
        int srow = wv*16 + (lane >> 4)*4 + j;
        gs[srow*33 + (lane & 15)]      = acc0[j];
        gs[srow*33 + 16 + (lane & 15)] = acc1[j];
      }

      // ---- gates ----
      {
        f16x2 p0 = __builtin_bit_cast(f16x2, x0);
        f16x2 p1 = __builtin_bit_cast(f16x2, x1);
        f16x2 p2 = __builtin_bit_cast(f16x2, x2);
        f16x2 p3 = __builtin_bit_cast(f16x2, x3);
        const int q = myseq*33;
        float vi0 = gs[q + hcA]         + (float)p0[0];
        float vi1 = gs[q + hcA + 1]     + (float)p0[1];
        float vf0 = gs[q + 8 + hcA]     + (float)p1[0];
        float vf1 = gs[q + 8 + hcA + 1] + (float)p1[1];
        float vg0 = gs[q + 16 + hcA]    + (float)p2[0];
        float vg1 = gs[q + 16 + hcA+1]  + (float)p2[1];
        float vo0 = gs[q + 24 + hcA]    + (float)p3[0];
        float vo1 = gs[q + 24 + hcA+1]  + (float)p3[1];
        if (act) {
          float i0 = sigf(vi0), f0 = sigf(vf0), G0 = tanh_(vg0), o0 = sigf(vo0);
          float i1 = sigf(vi1), f1 = sigf(vf1), G1 = tanh_(vg1), o1 = sigf(vo1);
          c0 = f0*c0 + i0*G0;
          c1 = f1*c1 + i1*G1;
          h0k = o0*tanh_(c0);
          h1k = o1*tanh_(c1);
          hold = (unsigned int)f2h(h0k) | ((unsigned int)f2h(h1k) << 16);
        }
      }

      // ---- 5. h-store FIRST (sc1, pred s<=mylen: one extra frozen store) ----
      if (s <= mylen) {
        asm volatile("global_store_dword %0, %1, %2 sc1"
                     :: "v"(st_voff), "v"(hold), "s"(hwrite) : "memory");
      }
      // out1 / hlast (plain cached, pred act)
      if (act) {
        int pos = dir ? (mylen - 1 - s) : s;
        if (LAYER == 0) {
          *(unsigned int*)(g_out1 + ((size_t)myseq*T_ + pos)*1024 + dir*H_ + col0 + hcA) = hold;
        } else {
          g_hlast[dir][myseq*H_ + col0 + hcA]     = h0k;
          g_hlast[dir][myseq*H_ + col0 + hcA + 1] = h1k;
        }
      }

      // ---- 6. xg(s+1) prefetch (rides across the barrier) ----
      {
        int s1 = s + 1;
        int p1 = dir ? (mylen - 1 - s1) : s1;
        p1 = p1 < 0 ? 0 : (p1 > mylen - 1 ? mylen - 1 : p1);
        const char* xr = xbase + (size_t)p1*4096;
        asm volatile("global_load_dword %0, %1, off"             : "=v"(nx0) : "v"(xr) : "memory");
        asm volatile("global_load_dword %0, %1, off offset:1024" : "=v"(nx1) : "v"(xr) : "memory");
        asm volatile("global_load_dword %0, %1, off offset:2048" : "=v"(nx2) : "v"(xr) : "memory");
        asm volatile("global_load_dword %0, %1, off offset:3072" : "=v"(nx3) : "v"(xr) : "memory");
      }

      // ---- 7. drain h-store only (out1/hlast + 4 prefetches keep flying) ----
      asm volatile("s_waitcnt vmcnt(4)" ::: "memory");
    }

    // ---- 8. rendezvous + fanout signal + reader-local poll ----
    asm volatile("s_barrier" ::: "memory");
    if (wv == 0) {
      unsigned int fv = (unsigned int)(s + 1);
      asm volatile("global_store_dword %0, %1, %2 sc1"
                   :: "v"(fan_voff), "v"(fv), "s"(flags) : "memory");
      const unsigned int tgt = fv;
      while (true) {
        unsigned int v;
        asm volatile("global_load_dword %0, %1, %2 sc1"
                     : "=v"(v) : "v"(pol_voff), "s"(flags) : "memory");
        asm volatile("s_waitcnt vmcnt(0)" ::: "memory");
        if (__all(v >= tgt)) break;
        __builtin_amdgcn_s_sleep(1);
      }
    }
    asm volatile("s_barrier" ::: "memory");
  }
}

// ---------------- final projection ----------------
__global__ void k_final(const float* __restrict__ w_out, const float* __restrict__ b_out,
                        float* __restrict__ out) {
  const int b = blockIdx.x;
  const int tid = threadIdx.x;
  float sum = 0.f;
  for (int k = tid; k < 1024; k += 256) {
    float h = (k < 512) ? g_hlast[0][b*H_ + k] : g_hlast[1][b*H_ + k - 512];
    sum += h * w_out[k];
  }
  __shared__ float red[256];
  red[tid] = sum;
  __syncthreads();
  for (int st = 128; st > 0; st >>= 1) {
    if (tid < st) red[tid] += red[tid + st];
    __syncthreads();
  }
  if (tid == 0) out[b] = 1.f/(1.f + __expf(-(red[0] + b_out[0])));
}

// ---------------- launch ----------------
extern "C" void kernel_launch(void* const* d_in, const int* in_sizes, int n_in,
                              void* d_out, int out_size, void* d_ws, size_t ws_size,
                              hipStream_t stream) {
  (void)in_sizes; (void)n_in; (void)d_ws; (void)ws_size; (void)out_size;
  const float* seqs    = (const float*)d_in[0];
  const int*   lens    = (const int*)d_in[1];
  const float* w_ih_l0 = (const float*)d_in[2];
  const float* w_hh_l0 = (const float*)d_in[3];
  const float* b_ih_l0 = (const float*)d_in[4];
  const float* b_hh_l0 = (const float*)d_in[5];
  const float* w_ih_l1 = (const float*)d_in[6];
  const float* w_hh_l1 = (const float*)d_in[7];
  const float* b_ih_l1 = (const float*)d_in[8];
  const float* b_hh_l1 = (const float*)d_in[9];
  const float* w_out   = (const float*)d_in[10];
  const float* b_out   = (const float*)d_in[11];
  float* outp = (float*)d_out;

  hipLaunchKernelGGL(k_init,   dim3(256),  dim3(256), 0, stream);
  hipLaunchKernelGGL(k_cvt_x,  dim3(2048), dim3(256), 0, stream, seqs);
  hipLaunchKernelGGL(k_cvt_w1, dim3(256),  dim3(256), 0, stream, w_ih_l0);
  hipLaunchKernelGGL(k_cvt_w2, dim3(512),  dim3(256), 0, stream, w_ih_l1);

  hipLaunchKernelGGL((k_xproj<0>), dim3(BT_/128, 16, 2), dim3(256), 0, stream,
                     b_ih_l0, b_hh_l0, lens);
  {
    void* args[] = { (void*)&w_hh_l0, (void*)&lens };
    hipError_t e = hipLaunchCooperativeKernel(k_scan<0>, dim3(128), dim3(256), args, 0u, stream);
    (void)e;
  }
  hipLaunchKernelGGL((k_xproj<1>), dim3(BT_/128, 16, 2), dim3(256), 0, stream,
                     b_ih_l1, b_hh_l1, lens);
  {
    void* args[] = { (void*)&w_hh_l1, (void*)&lens };
    hipError_t e = hipLaunchCooperativeKernel(k_scan<1>, dim3(128), dim3(256), args, 0u, stream);
    (void)e;
  }
  hipLaunchKernelGGL(k_final, dim3(64), dim3(256), 0, stream, w_out, b_out, outp);
}